// Round 7
// baseline (265.690 us; speedup 1.0000x reference)
//
#include <hip/hip_runtime.h>

// RWKV time mixing: LN -> token-shift mix -> 3x low-rank proj -> chunked scan
// -> output GEMM. B=4, T=2048, C=2048, R=256.
// Round 7: 8-phase-style GEMM (m201-class): 256x256 tile, BK=64, 8 waves,
// LDS = 2-K-tile dbuf of 8KB subtiles [parity][A|B][Mhalf][Khalf]. Per phase:
// 8 ds_read_b128 -> 2 global_load_lds -> 16 MFMA -> (vmcnt gate) -> barrier.
// Stage ledger: ph1/2 stage (t+1).kh1, ph3/4 stage (t+2).kh0; gates vmcnt(8)
// steady, 8->4->0 drain. XOR swizzle (0 conflicts, r3-verified) kept.

typedef __attribute__((ext_vector_type(8))) __bf16 bf16x8;
typedef __attribute__((ext_vector_type(4))) float f32x4;

static constexpr int Bb = 4, Tt = 2048, Cc = 2048, Rr = 256;
static constexpr int Mrows = Bb * Tt;      // 8192
static constexpr int NCH = 32, CLEN = 64;  // scan chunking

__device__ __forceinline__ unsigned short f2bf(float f) {
  union { float f; unsigned u; } a; a.f = f;
  unsigned r = (a.u + 0x7FFFu + ((a.u >> 16) & 1u)) >> 16;  // RNE
  return (unsigned short)r;
}
__device__ __forceinline__ float bf2f(unsigned short h) {
  union { unsigned u; float f; } a; a.u = ((unsigned)h) << 16;
  return a.f;
}

__device__ __forceinline__ void gload16(const void* g, void* l) {
  __builtin_amdgcn_global_load_lds(
      (const __attribute__((address_space(1))) void*)g,
      (__attribute__((address_space(3))) void*)l, 16, 0, 0);
}

// ---------------- weight prep ----------------------------------------------
__global__ void prep_weights(const float* __restrict__ wqa, const float* __restrict__ wka,
                             const float* __restrict__ wva, const float* __restrict__ wqb,
                             const float* __restrict__ wkb, const float* __restrict__ wvb,
                             const float* __restrict__ ow,  const float* __restrict__ td,
                             unsigned short* __restrict__ waT, unsigned short* __restrict__ wbT,
                             unsigned short* __restrict__ owT, float* __restrict__ decay,
                             float* __restrict__ decayL) {
  const int g = blockIdx.x * blockDim.x + threadIdx.x;
  const int stride = gridDim.x * blockDim.x;
  for (int i = g; i < 3 * Rr * Cc; i += stride) {
    int c = i & (Cc - 1); int jj = i >> 11; int p = jj >> 8; int r = jj & (Rr - 1);
    const float* w = (p == 0) ? wqa : ((p == 1) ? wka : wva);
    waT[i] = f2bf(w[(size_t)c * Rr + r]);
  }
  for (int i = g; i < 3 * Cc * Rr; i += stride) {
    int r = i & (Rr - 1); int d = (i >> 8) & (Cc - 1); int p = i >> 19;
    const float* w = (p == 0) ? wqb : ((p == 1) ? wkb : wvb);
    wbT[i] = f2bf(w[(size_t)r * Cc + d]);
  }
  for (int i = g; i < Cc * Cc; i += stride) owT[i] = f2bf(ow[i]);
  for (int i = g; i < Cc; i += stride) {
    float e = expf(td[i]);
    decay[i] = expf(-e);
    decayL[i] = expf(-(float)CLEN * e);
  }
}

// ---------------- fused LayerNorm + token-shift mix -------------------------
__global__ __launch_bounds__(256) void lnmix_kernel(
    const float* __restrict__ x, const float* __restrict__ gamma,
    const float* __restrict__ beta, unsigned short* __restrict__ mix) {
  const int m = blockIdx.x;
  const int t = m & (Tt - 1);
  const float* xr = x + (size_t)m * Cc;
  float s0 = 0.f, q0 = 0.f, s1 = 0.f, q1 = 0.f;
  float4 cur[2], prv[2];
#pragma unroll
  for (int r = 0; r < 2; ++r) {
    int i = threadIdx.x + r * 256;
    float4 v = ((const float4*)xr)[i];
    cur[r] = v;
    s0 += v.x + v.y + v.z + v.w;
    q0 += v.x * v.x + v.y * v.y + v.z * v.z + v.w * v.w;
  }
  if (t > 0) {
    const float* xp = xr - Cc;
#pragma unroll
    for (int r = 0; r < 2; ++r) {
      int i = threadIdx.x + r * 256;
      float4 v = ((const float4*)xp)[i];
      prv[r] = v;
      s1 += v.x + v.y + v.z + v.w;
      q1 += v.x * v.x + v.y * v.y + v.z * v.z + v.w * v.w;
    }
  }
#pragma unroll
  for (int off = 32; off; off >>= 1) {
    s0 += __shfl_down(s0, off); q0 += __shfl_down(q0, off);
    s1 += __shfl_down(s1, off); q1 += __shfl_down(q1, off);
  }
  __shared__ float red[4][4];
  __shared__ float bc[4];
  if ((threadIdx.x & 63) == 0) {
    int w = threadIdx.x >> 6;
    red[w][0] = s0; red[w][1] = q0; red[w][2] = s1; red[w][3] = q1;
  }
  __syncthreads();
  if (threadIdx.x == 0) {
    float a0 = 0, b0 = 0, a1 = 0, b1 = 0;
    for (int w = 0; w < 4; ++w) { a0 += red[w][0]; b0 += red[w][1]; a1 += red[w][2]; b1 += red[w][3]; }
    float mu0 = a0 * (1.f / Cc);
    bc[0] = mu0; bc[1] = rsqrtf(b0 * (1.f / Cc) - mu0 * mu0 + 1e-5f);
    float mu1 = a1 * (1.f / Cc);
    bc[2] = mu1; bc[3] = rsqrtf(b1 * (1.f / Cc) - mu1 * mu1 + 1e-5f);
  }
  __syncthreads();
  const float mu0 = bc[0], rs0 = bc[1], mu1 = bc[2], rs1 = bc[3];
#pragma unroll
  for (int r = 0; r < 2; ++r) {
    int i = threadIdx.x + r * 256;
    float4 g = ((const float4*)gamma)[i];
    float4 bb = ((const float4*)beta)[i];
    float4 v = cur[r];
    float mx = (v.x - mu0) * rs0 * g.x + bb.x;
    float my = (v.y - mu0) * rs0 * g.y + bb.y;
    float mz = (v.z - mu0) * rs0 * g.z + bb.z;
    float mw = (v.w - mu0) * rs0 * g.w + bb.w;
    if (t > 0) {
      float4 u = prv[r];
      mx = 0.5f * (mx + (u.x - mu1) * rs1 * g.x + bb.x);
      my = 0.5f * (my + (u.y - mu1) * rs1 * g.y + bb.y);
      mz = 0.5f * (mz + (u.z - mu1) * rs1 * g.z + bb.z);
      mw = 0.5f * (mw + (u.w - mu1) * rs1 * g.w + bb.w);
    } else {
      mx *= 0.5f; my *= 0.5f; mz *= 0.5f; mw *= 0.5f;
    }
    ushort4 o;
    o.x = f2bf(mx); o.y = f2bf(my); o.z = f2bf(mz); o.w = f2bf(mw);
    ((ushort4*)mix)[(size_t)m * 512 + i] = o;
  }
}

// ---------------- 256^2 BK=64 8-phase-style GEMM ----------------------------
// 512 threads = 8 waves (2 M x 4 N); wave tile 128x64; acc[8][4] f32x4.
// LDS (ushort idx): [parity]*32768 + {A:0,B:16384} + half*8192 + kh*4096
//   + row*32 + slot*8, subtile = 128 rows x 32 cols bf16 = 8 KB.
// Swizzle: 16B slot s of row r at s ^ ((r>>1)&3); gload_lds dest linear,
// global source col pre-swizzled, ds_read swizzled (0 conflicts).
// Phase (ih,kh): 8 ds_read_b128 -> stage 2 subtiles -> 16 MFMA -> gate -> bar.
// Ledger: ph1: stage (t+1).kh1 A; ph2: (t+1).kh1 B, gate vmcnt(8|0);
//         ph3: stage (t+2).kh0 A; ph4: (t+2).kh0 B, gate vmcnt(8|4|-).
template <bool STORE_BF16, bool ADD_BIAS>
__global__ __launch_bounds__(512, 1) void gemm8p(
    const unsigned short* __restrict__ A0p, long lda, long aStrideP,
    const unsigned short* __restrict__ B0p, long ldb, long bStrideP,
    void* c0, void* c1, void* c2, long ldc, int K,
    const float* __restrict__ bias, int nbx, int nby) {
  __shared__ unsigned short lds[65536];
  const int tid = threadIdx.x;
  const int nwg = gridDim.x;
  const int id = blockIdx.x;
  const int qq = nwg >> 3;
  const int swz = (id & 7) * qq + (id >> 3);
  const int per = nbx * nby;
  const int p = swz / per;
  const int r2 = swz - p * per;
  const int mblk = r2 / nbx;
  const int nblk = r2 - mblk * nbx;
  const unsigned short* A  = A0p + (long)p * aStrideP;
  const unsigned short* Bt = B0p + (long)p * bStrideP;
  void* Cout = (p == 0) ? c0 : (p == 1 ? c1 : c2);
  const long m0 = (long)mblk * 256, n0 = (long)nblk * 256;

  const int lane = tid & 63, wid = tid >> 6;
  const int wm = wid >> 2, wn = wid & 3;
  const int fr = lane & 15, fq = lane >> 4;

  // staging: thread -> subtile row tid>>2, linear 16B slot tid&3;
  // global source col pre-swizzled: s_src = (tid&3) ^ ((row>>1)&3).
  const int srow = tid >> 2;
  const int s_src = (tid & 3) ^ ((tid >> 3) & 3);
  const unsigned short* AgH0 = A + (m0 + srow) * lda + s_src * 8;
  const unsigned short* AgH1 = A + (m0 + 128 + srow) * lda + s_src * 8;
  const unsigned short* BgH0 = Bt + (n0 + srow) * ldb + s_src * 8;
  const unsigned short* BgH1 = Bt + (n0 + 128 + srow) * ldb + s_src * 8;

  // read side: logical slot fq of row rr lives at fq ^ ((rr>>1)&3) = fq ^ ((fr>>1)&3)
  const int swzs = fq ^ ((fr >> 1) & 3);
  const int aOff = wm * 8192 + fr * 32 + swzs * 8;                       // + P + kh*4096 + ih*2048 + i*512
  const int bOff = 16384 + (wn >> 1) * 8192 + ((wn & 1) * 64 + fr) * 32 + swzs * 8;  // + P + kh*4096 + j*512

  f32x4 acc[8][4];
#pragma unroll
  for (int i = 0; i < 8; ++i)
#pragma unroll
    for (int j = 0; j < 4; ++j) acc[i][j] = (f32x4){0.f, 0.f, 0.f, 0.f};

  const int NT = K >> 6;   // K-tiles of 64 (NT >= 3 for all our shapes)

  auto stageA2 = [&](int tt, int kh) {
    unsigned short* d = &lds[((tt & 1) << 15) + (kh << 12) + tid * 8];
    const long co = (long)tt * 64 + kh * 32;
    gload16(AgH0 + co, d);
    gload16(AgH1 + co, d + 8192);
  };
  auto stageB2 = [&](int tt, int kh) {
    unsigned short* d = &lds[((tt & 1) << 15) + 16384 + (kh << 12) + tid * 8];
    const long co = (long)tt * 64 + kh * 32;
    gload16(BgH0 + co, d);
    gload16(BgH1 + co, d + 8192);
  };

  // prologue: t0.kh0, t0.kh1, t1.kh0   (12 loads/thread)
  stageA2(0, 0); stageB2(0, 0);
  stageA2(0, 1); stageB2(0, 1);
  stageA2(1, 0); stageB2(1, 0);
  asm volatile("s_waitcnt vmcnt(8)" ::: "memory");  // t0.kh0 landed
  __builtin_amdgcn_s_barrier();
  __builtin_amdgcn_sched_barrier(0);

  for (int t = 0; t < NT; ++t) {
    const int P = (t & 1) << 15;
    const unsigned short* ap = &lds[P + aOff];
    const unsigned short* bp = &lds[P + bOff];

    // ---- ph1: ih=0, kh=0 ----
    {
      bf16x8 af[4], bf[4];
#pragma unroll
      for (int j = 0; j < 4; ++j) bf[j] = *(const bf16x8*)(bp + j * 512);
#pragma unroll
      for (int i = 0; i < 4; ++i) af[i] = *(const bf16x8*)(ap + i * 512);
      if (t + 1 < NT) stageA2(t + 1, 1);
      __builtin_amdgcn_s_setprio(1);
#pragma unroll
      for (int i = 0; i < 4; ++i)
#pragma unroll
        for (int j = 0; j < 4; ++j)
          acc[i][j] = __builtin_amdgcn_mfma_f32_16x16x32_bf16(af[i], bf[j], acc[i][j], 0, 0, 0);
      __builtin_amdgcn_s_setprio(0);
      __builtin_amdgcn_s_barrier();
      __builtin_amdgcn_sched_barrier(0);
    }
    // ---- ph2: ih=1, kh=0 ----
    {
      bf16x8 af[4], bf[4];
#pragma unroll
      for (int j = 0; j < 4; ++j) bf[j] = *(const bf16x8*)(bp + j * 512);
#pragma unroll
      for (int i = 0; i < 4; ++i) af[i] = *(const bf16x8*)(ap + 2048 + i * 512);
      if (t + 1 < NT) stageB2(t + 1, 1);
      __builtin_amdgcn_s_setprio(1);
#pragma unroll
      for (int i = 0; i < 4; ++i)
#pragma unroll
        for (int j = 0; j < 4; ++j)
          acc[4 + i][j] = __builtin_amdgcn_mfma_f32_16x16x32_bf16(af[i], bf[j], acc[4 + i][j], 0, 0, 0);
      __builtin_amdgcn_s_setprio(0);
      if (t + 1 < NT) asm volatile("s_waitcnt vmcnt(8)" ::: "memory");
      else            asm volatile("s_waitcnt vmcnt(0)" ::: "memory");
      __builtin_amdgcn_s_barrier();
      __builtin_amdgcn_sched_barrier(0);
    }
    // ---- ph3: ih=0, kh=1 ----
    {
      bf16x8 af[4], bf[4];
#pragma unroll
      for (int j = 0; j < 4; ++j) bf[j] = *(const bf16x8*)(bp + 4096 + j * 512);
#pragma unroll
      for (int i = 0; i < 4; ++i) af[i] = *(const bf16x8*)(ap + 4096 + i * 512);
      if (t + 2 < NT) stageA2(t + 2, 0);
      __builtin_amdgcn_s_setprio(1);
#pragma unroll
      for (int i = 0; i < 4; ++i)
#pragma unroll
        for (int j = 0; j < 4; ++j)
          acc[i][j] = __builtin_amdgcn_mfma_f32_16x16x32_bf16(af[i], bf[j], acc[i][j], 0, 0, 0);
      __builtin_amdgcn_s_setprio(0);
      __builtin_amdgcn_s_barrier();
      __builtin_amdgcn_sched_barrier(0);
    }
    // ---- ph4: ih=1, kh=1 ----
    {
      bf16x8 af[4], bf[4];
#pragma unroll
      for (int j = 0; j < 4; ++j) bf[j] = *(const bf16x8*)(bp + 4096 + j * 512);
#pragma unroll
      for (int i = 0; i < 4; ++i) af[i] = *(const bf16x8*)(ap + 4096 + 2048 + i * 512);
      if (t + 2 < NT) stageB2(t + 2, 0);
      __builtin_amdgcn_s_setprio(1);
#pragma unroll
      for (int i = 0; i < 4; ++i)
#pragma unroll
        for (int j = 0; j < 4; ++j)
          acc[4 + i][j] = __builtin_amdgcn_mfma_f32_16x16x32_bf16(af[i], bf[j], acc[4 + i][j], 0, 0, 0);
      __builtin_amdgcn_s_setprio(0);
      if (t + 2 < NT)      asm volatile("s_waitcnt vmcnt(8)" ::: "memory");
      else if (t + 1 < NT) asm volatile("s_waitcnt vmcnt(4)" ::: "memory");
      __builtin_amdgcn_s_barrier();
      __builtin_amdgcn_sched_barrier(0);
    }
  }

#pragma unroll
  for (int j = 0; j < 4; ++j) {
    const long col = n0 + wn * 64 + j * 16 + fr;
    const float bv = ADD_BIAS ? bias[col] : 0.0f;
#pragma unroll
    for (int i = 0; i < 8; ++i) {
      const long row0 = m0 + wm * 128 + i * 16 + fq * 4;
#pragma unroll
      for (int r = 0; r < 4; ++r) {
        float val = acc[i][j][r] + bv;
        if (STORE_BF16)
          ((unsigned short*)Cout)[(row0 + r) * ldc + col] = f2bf(val);
        else
          ((float*)Cout)[(row0 + r) * ldc + col] = val;
      }
    }
  }
}

// ---------------- split-K combine for G1 ------------------------------------
__global__ void addcvt_kernel(const float* __restrict__ p0, const float* __restrict__ p1,
                              unsigned short* __restrict__ o, int n4) {
  for (int i = blockIdx.x * blockDim.x + threadIdx.x; i < n4; i += gridDim.x * blockDim.x) {
    float4 a = ((const float4*)p0)[i];
    float4 b = ((const float4*)p1)[i];
    ushort4 r;
    r.x = f2bf(a.x + b.x); r.y = f2bf(a.y + b.y);
    r.z = f2bf(a.z + b.z); r.w = f2bf(a.w + b.w);
    ((ushort4*)o)[i] = r;
  }
}

// ---------------- chunked scan ---------------------------------------------
__global__ void scan_phaseA(const unsigned short* __restrict__ k, const unsigned short* __restrict__ v,
                            const float* __restrict__ decay, float* __restrict__ hend) {
  const int g = blockIdx.x * 256 + threadIdx.x;
  const int c = g & (Cc - 1);
  const int j = (g >> 11) & (NCH - 1);
  const int b = g >> 16;
  const float d = decay[c];
  size_t base = ((size_t)(b * Tt + j * CLEN)) * Cc + c;
  float h = 0.f;
#pragma unroll 8
  for (int s = 0; s < CLEN; ++s) {
    size_t idx = base + (size_t)s * Cc;
    float kv = bf2f(k[idx]) * bf2f(v[idx]);
    h = fmaf(d, h, kv);
  }
  hend[(size_t)(b * NCH + j) * Cc + c] = h;
}

__global__ void scan_combine(const float* __restrict__ hend, const float* __restrict__ h0,
                             const float* __restrict__ decayL, float* __restrict__ Hin,
                             float* __restrict__ hfinal) {
  const int g = blockIdx.x * 256 + threadIdx.x;
  const int c = g & (Cc - 1);
  float H = h0[g];
  const float dl = decayL[c];
  const int b = g >> 11;
  for (int j = 0; j < NCH; ++j) {
    size_t idx = (size_t)(b * NCH + j) * Cc + c;
    Hin[idx] = H;
    H = fmaf(dl, H, hend[idx]);
  }
  hfinal[g] = H;
}

__global__ void scan_phaseB(const unsigned short* __restrict__ q, const unsigned short* __restrict__ k,
                            const unsigned short* __restrict__ v, const float* __restrict__ decay,
                            const float* __restrict__ Hin, unsigned short* __restrict__ ys) {
  const int g = blockIdx.x * 256 + threadIdx.x;
  const int c = g & (Cc - 1);
  const int j = (g >> 11) & (NCH - 1);
  const int b = g >> 16;
  const float d = decay[c];
  float h = Hin[(size_t)(b * NCH + j) * Cc + c];
  size_t base = ((size_t)(b * Tt + j * CLEN)) * Cc + c;
#pragma unroll 4
  for (int s = 0; s < CLEN; ++s) {
    size_t idx = base + (size_t)s * Cc;
    float kv = bf2f(k[idx]) * bf2f(v[idx]);
    h = fmaf(d, h, kv);
    float qq = bf2f(q[idx]);
    float sg = 1.f / (1.f + expf(-qq));
    ys[idx] = f2bf(sg * h);
  }
}

// ---------------- launch ----------------------------------------------------
extern "C" void kernel_launch(void* const* d_in, const int* in_sizes, int n_in,
                              void* d_out, int out_size, void* d_ws, size_t ws_size,
                              hipStream_t stream) {
  const float* x   = (const float*)d_in[0];
  const float* h0  = (const float*)d_in[1];
  const float* gam = (const float*)d_in[2];
  const float* bet = (const float*)d_in[3];
  const float* wqa = (const float*)d_in[4];
  const float* wqb = (const float*)d_in[5];
  const float* wka = (const float*)d_in[6];
  const float* wkb = (const float*)d_in[7];
  const float* wva = (const float*)d_in[8];
  const float* wvb = (const float*)d_in[9];
  const float* ow  = (const float*)d_in[10];
  const float* ob  = (const float*)d_in[11];
  const float* td  = (const float*)d_in[12];
  float* out = (float*)d_out;

  char* ws = (char*)d_ws;
  unsigned short* waT   = (unsigned short*)(ws + 0);          //  3,145,728
  unsigned short* wbT   = (unsigned short*)(ws + 3145728);    //  3,145,728
  unsigned short* owT   = (unsigned short*)(ws + 6291456);    //  8,388,608
  float*          decay = (float*)(ws + 14680064);
  float*          decayL= (float*)(ws + 14688256);
  unsigned short* mixb  = (unsigned short*)(ws + 14761984);   // 33,554,432 (reused as ys)
  unsigned short* tmp   = (unsigned short*)(ws + 48316416);   // 12,582,912
  unsigned short* vp    = (unsigned short*)(ws + 60899328);   // 33,554,432
  float*          hend  = (float*)(ws + 94453760);
  float*          Hin   = (float*)(ws + 95502336);
  // staged in d_out (dead before overwritten): G1 f32 partials, then q,k bf16
  float* P0 = (float*)d_out;                                  // 25.2 MB
  float* P1 = P0 + (size_t)Mrows * 768;                       // 25.2 MB
  unsigned short* qp = (unsigned short*)d_out;
  unsigned short* kp = qp + (size_t)Mrows * Cc;
  float* hfinal = out + (size_t)Mrows * Cc;
  unsigned short* ysb = mixb;

  prep_weights<<<1024, 256, 0, stream>>>(wqa, wka, wva, wqb, wkb, wvb, ow, td,
                                         waT, wbT, owT, decay, decayL);
  lnmix_kernel<<<Mrows, 256, 0, stream>>>(x, gam, bet, mixb);

  // G1 split-K x2: P_p[8192][768] = mix[:, p*1024:(p+1)*1024] @ waT_half
  // (192 blocks: nbx=3, nby=32, p = K-half; NT=16)
  gemm8p<false, false><<<192, 512, 0, stream>>>(
      mixb, Cc, 1024, waT, Cc, 1024,
      P0, P1, nullptr, 768, 1024, nullptr, 3, 32);
  addcvt_kernel<<<1024, 256, 0, stream>>>(P0, P1, tmp, Mrows * 768 / 4);

  // G2 grouped: q/k/v[8192][2048] = tmp_p @ w_b_p   (768 blocks; NT=4)
  gemm8p<true, false><<<768, 512, 0, stream>>>(
      tmp, 768, 256, wbT, Rr, (long)Cc * Rr,
      qp, kp, vp, Cc, Rr, nullptr, 8, 32);

  scan_phaseA<<<(Bb * NCH * Cc) / 256, 256, 0, stream>>>(kp, vp, decay, hend);
  scan_combine<<<(Bb * Cc) / 256, 256, 0, stream>>>(hend, h0, decayL, Hin, hfinal);
  scan_phaseB<<<(Bb * NCH * Cc) / 256, 256, 0, stream>>>(qp, kp, vp, decay, Hin, ysb);

  // Gout: out = ys @ out_w^T + out_b   (256 blocks; NT=32)
  gemm8p<false, true><<<256, 512, 0, stream>>>(
      ysb, Cc, 0, owT, Cc, 0,
      out, out, out, Cc, Cc, ob, 8, 32);
}

// Round 8
// 264.475 us; speedup vs baseline: 1.0046x; 1.0046x over previous
//
#include <hip/hip_runtime.h>

// RWKV time mixing: LN -> token-shift mix -> 3x low-rank proj -> chunked scan
// -> output GEMM. B=4, T=2048, C=2048, R=256.
// Round 8: m201-canonical two-barrier phases: {reads+stage -> barrier ->
// MFMA -> [gate] -> barrier}; reads issue BEFORE the first barrier so ds_read
// latency hides under barrier-wait and wave-skew overlaps LDS with MFMA.
// B fragments persist across the ih0/ih1 phase pair (-25% LDS reads).
// Ledger identical to r7 (race-free): ph1/2 stage (t+1).kh1, ph3/4 stage
// (t+2).kh0; gates vmcnt(8) steady at ph2/ph4, drain 0/4.

typedef __attribute__((ext_vector_type(8))) __bf16 bf16x8;
typedef __attribute__((ext_vector_type(4))) float f32x4;

static constexpr int Bb = 4, Tt = 2048, Cc = 2048, Rr = 256;
static constexpr int Mrows = Bb * Tt;      // 8192
static constexpr int NCH = 32, CLEN = 64;  // scan chunking

__device__ __forceinline__ unsigned short f2bf(float f) {
  union { float f; unsigned u; } a; a.f = f;
  unsigned r = (a.u + 0x7FFFu + ((a.u >> 16) & 1u)) >> 16;  // RNE
  return (unsigned short)r;
}
__device__ __forceinline__ float bf2f(unsigned short h) {
  union { unsigned u; float f; } a; a.u = ((unsigned)h) << 16;
  return a.f;
}

__device__ __forceinline__ void gload16(const void* g, void* l) {
  __builtin_amdgcn_global_load_lds(
      (const __attribute__((address_space(1))) void*)g,
      (__attribute__((address_space(3))) void*)l, 16, 0, 0);
}

// ---------------- weight prep ----------------------------------------------
__global__ void prep_weights(const float* __restrict__ wqa, const float* __restrict__ wka,
                             const float* __restrict__ wva, const float* __restrict__ wqb,
                             const float* __restrict__ wkb, const float* __restrict__ wvb,
                             const float* __restrict__ ow,  const float* __restrict__ td,
                             unsigned short* __restrict__ waT, unsigned short* __restrict__ wbT,
                             unsigned short* __restrict__ owT, float* __restrict__ decay,
                             float* __restrict__ decayL) {
  const int g = blockIdx.x * blockDim.x + threadIdx.x;
  const int stride = gridDim.x * blockDim.x;
  for (int i = g; i < 3 * Rr * Cc; i += stride) {
    int c = i & (Cc - 1); int jj = i >> 11; int p = jj >> 8; int r = jj & (Rr - 1);
    const float* w = (p == 0) ? wqa : ((p == 1) ? wka : wva);
    waT[i] = f2bf(w[(size_t)c * Rr + r]);
  }
  for (int i = g; i < 3 * Cc * Rr; i += stride) {
    int r = i & (Rr - 1); int d = (i >> 8) & (Cc - 1); int p = i >> 19;
    const float* w = (p == 0) ? wqb : ((p == 1) ? wkb : wvb);
    wbT[i] = f2bf(w[(size_t)r * Cc + d]);
  }
  for (int i = g; i < Cc * Cc; i += stride) owT[i] = f2bf(ow[i]);
  for (int i = g; i < Cc; i += stride) {
    float e = expf(td[i]);
    decay[i] = expf(-e);
    decayL[i] = expf(-(float)CLEN * e);
  }
}

// ---------------- fused LayerNorm + token-shift mix -------------------------
__global__ __launch_bounds__(256) void lnmix_kernel(
    const float* __restrict__ x, const float* __restrict__ gamma,
    const float* __restrict__ beta, unsigned short* __restrict__ mix) {
  const int m = blockIdx.x;
  const int t = m & (Tt - 1);
  const float* xr = x + (size_t)m * Cc;
  float s0 = 0.f, q0 = 0.f, s1 = 0.f, q1 = 0.f;
  float4 cur[2], prv[2];
#pragma unroll
  for (int r = 0; r < 2; ++r) {
    int i = threadIdx.x + r * 256;
    float4 v = ((const float4*)xr)[i];
    cur[r] = v;
    s0 += v.x + v.y + v.z + v.w;
    q0 += v.x * v.x + v.y * v.y + v.z * v.z + v.w * v.w;
  }
  if (t > 0) {
    const float* xp = xr - Cc;
#pragma unroll
    for (int r = 0; r < 2; ++r) {
      int i = threadIdx.x + r * 256;
      float4 v = ((const float4*)xp)[i];
      prv[r] = v;
      s1 += v.x + v.y + v.z + v.w;
      q1 += v.x * v.x + v.y * v.y + v.z * v.z + v.w * v.w;
    }
  }
#pragma unroll
  for (int off = 32; off; off >>= 1) {
    s0 += __shfl_down(s0, off); q0 += __shfl_down(q0, off);
    s1 += __shfl_down(s1, off); q1 += __shfl_down(q1, off);
  }
  __shared__ float red[4][4];
  __shared__ float bc[4];
  if ((threadIdx.x & 63) == 0) {
    int w = threadIdx.x >> 6;
    red[w][0] = s0; red[w][1] = q0; red[w][2] = s1; red[w][3] = q1;
  }
  __syncthreads();
  if (threadIdx.x == 0) {
    float a0 = 0, b0 = 0, a1 = 0, b1 = 0;
    for (int w = 0; w < 4; ++w) { a0 += red[w][0]; b0 += red[w][1]; a1 += red[w][2]; b1 += red[w][3]; }
    float mu0 = a0 * (1.f / Cc);
    bc[0] = mu0; bc[1] = rsqrtf(b0 * (1.f / Cc) - mu0 * mu0 + 1e-5f);
    float mu1 = a1 * (1.f / Cc);
    bc[2] = mu1; bc[3] = rsqrtf(b1 * (1.f / Cc) - mu1 * mu1 + 1e-5f);
  }
  __syncthreads();
  const float mu0 = bc[0], rs0 = bc[1], mu1 = bc[2], rs1 = bc[3];
#pragma unroll
  for (int r = 0; r < 2; ++r) {
    int i = threadIdx.x + r * 256;
    float4 g = ((const float4*)gamma)[i];
    float4 bb = ((const float4*)beta)[i];
    float4 v = cur[r];
    float mx = (v.x - mu0) * rs0 * g.x + bb.x;
    float my = (v.y - mu0) * rs0 * g.y + bb.y;
    float mz = (v.z - mu0) * rs0 * g.z + bb.z;
    float mw = (v.w - mu0) * rs0 * g.w + bb.w;
    if (t > 0) {
      float4 u = prv[r];
      mx = 0.5f * (mx + (u.x - mu1) * rs1 * g.x + bb.x);
      my = 0.5f * (my + (u.y - mu1) * rs1 * g.y + bb.y);
      mz = 0.5f * (mz + (u.z - mu1) * rs1 * g.z + bb.z);
      mw = 0.5f * (mw + (u.w - mu1) * rs1 * g.w + bb.w);
    } else {
      mx *= 0.5f; my *= 0.5f; mz *= 0.5f; mw *= 0.5f;
    }
    ushort4 o;
    o.x = f2bf(mx); o.y = f2bf(my); o.z = f2bf(mz); o.w = f2bf(mw);
    ((ushort4*)mix)[(size_t)m * 512 + i] = o;
  }
}

// ---------------- 256^2 BK=64 two-barrier-phase GEMM ------------------------
// 512 threads = 8 waves (2 M x 4 N); wave tile 128x64; acc[8][4] f32x4.
// LDS (ushort idx): [parity]*32768 + {A:0,B:16384} + half*8192 + kh*4096
//   + row*32 + slot*8, subtile = 128 rows x 32 cols bf16 = 8 KB.
// Swizzle: 16B slot s of row r at s ^ ((r>>1)&3); gload_lds dest linear,
// global source col pre-swizzled, ds_read swizzled (0 conflicts).
// Phase: {reads + stage -> SB -> s_barrier -> SB -> setprio1 16 MFMA setprio0
//   -> [vmcnt gate at ph2/ph4] -> s_barrier -> SB}.  bf persists ih0->ih1.
template <bool STORE_BF16, bool ADD_BIAS>
__global__ __launch_bounds__(512, 1) void gemm8p(
    const unsigned short* __restrict__ A0p, long lda, long aStrideP,
    const unsigned short* __restrict__ B0p, long ldb, long bStrideP,
    void* c0, void* c1, void* c2, long ldc, int K,
    const float* __restrict__ bias, int nbx, int nby) {
  __shared__ unsigned short lds[65536];
  const int tid = threadIdx.x;
  const int nwg = gridDim.x;
  const int id = blockIdx.x;
  const int qq = nwg >> 3;
  const int swz = (id & 7) * qq + (id >> 3);
  const int per = nbx * nby;
  const int p = swz / per;
  const int r2 = swz - p * per;
  const int mblk = r2 / nbx;
  const int nblk = r2 - mblk * nbx;
  const unsigned short* A  = A0p + (long)p * aStrideP;
  const unsigned short* Bt = B0p + (long)p * bStrideP;
  void* Cout = (p == 0) ? c0 : (p == 1 ? c1 : c2);
  const long m0 = (long)mblk * 256, n0 = (long)nblk * 256;

  const int lane = tid & 63, wid = tid >> 6;
  const int wm = wid >> 2, wn = wid & 3;
  const int fr = lane & 15, fq = lane >> 4;

  const int srow = tid >> 2;
  const int s_src = (tid & 3) ^ ((tid >> 3) & 3);
  const unsigned short* AgH0 = A + (m0 + srow) * lda + s_src * 8;
  const unsigned short* AgH1 = A + (m0 + 128 + srow) * lda + s_src * 8;
  const unsigned short* BgH0 = Bt + (n0 + srow) * ldb + s_src * 8;
  const unsigned short* BgH1 = Bt + (n0 + 128 + srow) * ldb + s_src * 8;

  const int swzs = fq ^ ((fr >> 1) & 3);
  const int aOff = wm * 8192 + fr * 32 + swzs * 8;
  const int bOff = 16384 + (wn >> 1) * 8192 + ((wn & 1) * 64 + fr) * 32 + swzs * 8;

  f32x4 acc[8][4];
#pragma unroll
  for (int i = 0; i < 8; ++i)
#pragma unroll
    for (int j = 0; j < 4; ++j) acc[i][j] = (f32x4){0.f, 0.f, 0.f, 0.f};

  const int NT = K >> 6;   // K-tiles of 64

  auto stageA2 = [&](int tt, int kh) {
    unsigned short* d = &lds[((tt & 1) << 15) + (kh << 12) + tid * 8];
    const long co = (long)tt * 64 + kh * 32;
    gload16(AgH0 + co, d);
    gload16(AgH1 + co, d + 8192);
  };
  auto stageB2 = [&](int tt, int kh) {
    unsigned short* d = &lds[((tt & 1) << 15) + 16384 + (kh << 12) + tid * 8];
    const long co = (long)tt * 64 + kh * 32;
    gload16(BgH0 + co, d);
    gload16(BgH1 + co, d + 8192);
  };

  // prologue: t0.kh0, t0.kh1, t1.kh0   (12 loads/thread)
  stageA2(0, 0); stageB2(0, 0);
  stageA2(0, 1); stageB2(0, 1);
  stageA2(1, 0); stageB2(1, 0);
  asm volatile("s_waitcnt vmcnt(8)" ::: "memory");  // t0.kh0 landed
  __builtin_amdgcn_s_barrier();
  __builtin_amdgcn_sched_barrier(0);

  for (int t = 0; t < NT; ++t) {
    const int P = (t & 1) << 15;
    const unsigned short* ap = &lds[P + aOff];
    const unsigned short* bp = &lds[P + bOff];
    bf16x8 bf[4], af[4];

    // ---- ph1 (ih0,kh0): read bf(kh0)+af; stage A(t+1).kh1 ----
#pragma unroll
    for (int j = 0; j < 4; ++j) bf[j] = *(const bf16x8*)(bp + j * 512);
#pragma unroll
    for (int i = 0; i < 4; ++i) af[i] = *(const bf16x8*)(ap + i * 512);
    if (t + 1 < NT) stageA2(t + 1, 1);
    __builtin_amdgcn_sched_barrier(0);
    __builtin_amdgcn_s_barrier();
    __builtin_amdgcn_sched_barrier(0);
    __builtin_amdgcn_s_setprio(1);
#pragma unroll
    for (int i = 0; i < 4; ++i)
#pragma unroll
      for (int j = 0; j < 4; ++j)
        acc[i][j] = __builtin_amdgcn_mfma_f32_16x16x32_bf16(af[i], bf[j], acc[i][j], 0, 0, 0);
    __builtin_amdgcn_s_setprio(0);
    __builtin_amdgcn_s_barrier();
    __builtin_amdgcn_sched_barrier(0);

    // ---- ph2 (ih1,kh0): read af (bf reused); stage B(t+1).kh1; gate ----
#pragma unroll
    for (int i = 0; i < 4; ++i) af[i] = *(const bf16x8*)(ap + 2048 + i * 512);
    if (t + 1 < NT) stageB2(t + 1, 1);
    __builtin_amdgcn_sched_barrier(0);
    __builtin_amdgcn_s_barrier();
    __builtin_amdgcn_sched_barrier(0);
    __builtin_amdgcn_s_setprio(1);
#pragma unroll
    for (int i = 0; i < 4; ++i)
#pragma unroll
      for (int j = 0; j < 4; ++j)
        acc[4 + i][j] = __builtin_amdgcn_mfma_f32_16x16x32_bf16(af[i], bf[j], acc[4 + i][j], 0, 0, 0);
    __builtin_amdgcn_s_setprio(0);
    if (t + 1 < NT) asm volatile("s_waitcnt vmcnt(8)" ::: "memory");
    else            asm volatile("s_waitcnt vmcnt(0)" ::: "memory");
    __builtin_amdgcn_s_barrier();
    __builtin_amdgcn_sched_barrier(0);

    // ---- ph3 (ih0,kh1): read bf(kh1)+af; stage A(t+2).kh0 ----
#pragma unroll
    for (int j = 0; j < 4; ++j) bf[j] = *(const bf16x8*)(bp + 4096 + j * 512);
#pragma unroll
    for (int i = 0; i < 4; ++i) af[i] = *(const bf16x8*)(ap + 4096 + i * 512);
    if (t + 2 < NT) stageA2(t + 2, 0);
    __builtin_amdgcn_sched_barrier(0);
    __builtin_amdgcn_s_barrier();
    __builtin_amdgcn_sched_barrier(0);
    __builtin_amdgcn_s_setprio(1);
#pragma unroll
    for (int i = 0; i < 4; ++i)
#pragma unroll
      for (int j = 0; j < 4; ++j)
        acc[i][j] = __builtin_amdgcn_mfma_f32_16x16x32_bf16(af[i], bf[j], acc[i][j], 0, 0, 0);
    __builtin_amdgcn_s_setprio(0);
    __builtin_amdgcn_s_barrier();
    __builtin_amdgcn_sched_barrier(0);

    // ---- ph4 (ih1,kh1): read af (bf reused); stage B(t+2).kh0; gate ----
#pragma unroll
    for (int i = 0; i < 4; ++i) af[i] = *(const bf16x8*)(ap + 4096 + 2048 + i * 512);
    if (t + 2 < NT) stageB2(t + 2, 0);
    __builtin_amdgcn_sched_barrier(0);
    __builtin_amdgcn_s_barrier();
    __builtin_amdgcn_sched_barrier(0);
    __builtin_amdgcn_s_setprio(1);
#pragma unroll
    for (int i = 0; i < 4; ++i)
#pragma unroll
      for (int j = 0; j < 4; ++j)
        acc[4 + i][j] = __builtin_amdgcn_mfma_f32_16x16x32_bf16(af[i], bf[j], acc[4 + i][j], 0, 0, 0);
    __builtin_amdgcn_s_setprio(0);
    if (t + 2 < NT)      asm volatile("s_waitcnt vmcnt(8)" ::: "memory");
    else if (t + 1 < NT) asm volatile("s_waitcnt vmcnt(4)" ::: "memory");
    __builtin_amdgcn_s_barrier();
    __builtin_amdgcn_sched_barrier(0);
  }

#pragma unroll
  for (int j = 0; j < 4; ++j) {
    const long col = n0 + wn * 64 + j * 16 + fr;
    const float bv = ADD_BIAS ? bias[col] : 0.0f;
#pragma unroll
    for (int i = 0; i < 8; ++i) {
      const long row0 = m0 + wm * 128 + i * 16 + fq * 4;
#pragma unroll
      for (int r = 0; r < 4; ++r) {
        float val = acc[i][j][r] + bv;
        if (STORE_BF16)
          ((unsigned short*)Cout)[(row0 + r) * ldc + col] = f2bf(val);
        else
          ((float*)Cout)[(row0 + r) * ldc + col] = val;
      }
    }
  }
}

// ---------------- split-K combine for G1 ------------------------------------
__global__ void addcvt_kernel(const float* __restrict__ p0, const float* __restrict__ p1,
                              unsigned short* __restrict__ o, int n4) {
  for (int i = blockIdx.x * blockDim.x + threadIdx.x; i < n4; i += gridDim.x * blockDim.x) {
    float4 a = ((const float4*)p0)[i];
    float4 b = ((const float4*)p1)[i];
    ushort4 r;
    r.x = f2bf(a.x + b.x); r.y = f2bf(a.y + b.y);
    r.z = f2bf(a.z + b.z); r.w = f2bf(a.w + b.w);
    ((ushort4*)o)[i] = r;
  }
}

// ---------------- chunked scan ---------------------------------------------
__global__ void scan_phaseA(const unsigned short* __restrict__ k, const unsigned short* __restrict__ v,
                            const float* __restrict__ decay, float* __restrict__ hend) {
  const int g = blockIdx.x * 256 + threadIdx.x;
  const int c = g & (Cc - 1);
  const int j = (g >> 11) & (NCH - 1);
  const int b = g >> 16;
  const float d = decay[c];
  size_t base = ((size_t)(b * Tt + j * CLEN)) * Cc + c;
  float h = 0.f;
#pragma unroll 8
  for (int s = 0; s < CLEN; ++s) {
    size_t idx = base + (size_t)s * Cc;
    float kv = bf2f(k[idx]) * bf2f(v[idx]);
    h = fmaf(d, h, kv);
  }
  hend[(size_t)(b * NCH + j) * Cc + c] = h;
}

__global__ void scan_combine(const float* __restrict__ hend, const float* __restrict__ h0,
                             const float* __restrict__ decayL, float* __restrict__ Hin,
                             float* __restrict__ hfinal) {
  const int g = blockIdx.x * 256 + threadIdx.x;
  const int c = g & (Cc - 1);
  float H = h0[g];
  const float dl = decayL[c];
  const int b = g >> 11;
  for (int j = 0; j < NCH; ++j) {
    size_t idx = (size_t)(b * NCH + j) * Cc + c;
    Hin[idx] = H;
    H = fmaf(dl, H, hend[idx]);
  }
  hfinal[g] = H;
}

__global__ void scan_phaseB(const unsigned short* __restrict__ q, const unsigned short* __restrict__ k,
                            const unsigned short* __restrict__ v, const float* __restrict__ decay,
                            const float* __restrict__ Hin, unsigned short* __restrict__ ys) {
  const int g = blockIdx.x * 256 + threadIdx.x;
  const int c = g & (Cc - 1);
  const int j = (g >> 11) & (NCH - 1);
  const int b = g >> 16;
  const float d = decay[c];
  float h = Hin[(size_t)(b * NCH + j) * Cc + c];
  size_t base = ((size_t)(b * Tt + j * CLEN)) * Cc + c;
#pragma unroll 4
  for (int s = 0; s < CLEN; ++s) {
    size_t idx = base + (size_t)s * Cc;
    float kv = bf2f(k[idx]) * bf2f(v[idx]);
    h = fmaf(d, h, kv);
    float qq = bf2f(q[idx]);
    float sg = 1.f / (1.f + expf(-qq));
    ys[idx] = f2bf(sg * h);
  }
}

// ---------------- launch ----------------------------------------------------
extern "C" void kernel_launch(void* const* d_in, const int* in_sizes, int n_in,
                              void* d_out, int out_size, void* d_ws, size_t ws_size,
                              hipStream_t stream) {
  const float* x   = (const float*)d_in[0];
  const float* h0  = (const float*)d_in[1];
  const float* gam = (const float*)d_in[2];
  const float* bet = (const float*)d_in[3];
  const float* wqa = (const float*)d_in[4];
  const float* wqb = (const float*)d_in[5];
  const float* wka = (const float*)d_in[6];
  const float* wkb = (const float*)d_in[7];
  const float* wva = (const float*)d_in[8];
  const float* wvb = (const float*)d_in[9];
  const float* ow  = (const float*)d_in[10];
  const float* ob  = (const float*)d_in[11];
  const float* td  = (const float*)d_in[12];
  float* out = (float*)d_out;

  char* ws = (char*)d_ws;
  unsigned short* waT   = (unsigned short*)(ws + 0);          //  3,145,728
  unsigned short* wbT   = (unsigned short*)(ws + 3145728);    //  3,145,728
  unsigned short* owT   = (unsigned short*)(ws + 6291456);    //  8,388,608
  float*          decay = (float*)(ws + 14680064);
  float*          decayL= (float*)(ws + 14688256);
  unsigned short* mixb  = (unsigned short*)(ws + 14761984);   // 33,554,432 (reused as ys)
  unsigned short* tmp   = (unsigned short*)(ws + 48316416);   // 12,582,912
  unsigned short* vp    = (unsigned short*)(ws + 60899328);   // 33,554,432
  float*          hend  = (float*)(ws + 94453760);
  float*          Hin   = (float*)(ws + 95502336);
  // staged in d_out (dead before overwritten): G1 f32 partials, then q,k bf16
  float* P0 = (float*)d_out;                                  // 25.2 MB
  float* P1 = P0 + (size_t)Mrows * 768;                       // 25.2 MB
  unsigned short* qp = (unsigned short*)d_out;
  unsigned short* kp = qp + (size_t)Mrows * Cc;
  float* hfinal = out + (size_t)Mrows * Cc;
  unsigned short* ysb = mixb;

  prep_weights<<<1024, 256, 0, stream>>>(wqa, wka, wva, wqb, wkb, wvb, ow, td,
                                         waT, wbT, owT, decay, decayL);
  lnmix_kernel<<<Mrows, 256, 0, stream>>>(x, gam, bet, mixb);

  // G1 split-K x2: P_p[8192][768] = mix[:, p*1024:(p+1)*1024] @ waT_half
  // (192 blocks: nbx=3, nby=32, p = K-half; NT=16)
  gemm8p<false, false><<<192, 512, 0, stream>>>(
      mixb, Cc, 1024, waT, Cc, 1024,
      P0, P1, nullptr, 768, 1024, nullptr, 3, 32);
  addcvt_kernel<<<1024, 256, 0, stream>>>(P0, P1, tmp, Mrows * 768 / 4);

  // G2 grouped: q/k/v[8192][2048] = tmp_p @ w_b_p   (768 blocks; NT=4)
  gemm8p<true, false><<<768, 512, 0, stream>>>(
      tmp, 768, 256, wbT, Rr, (long)Cc * Rr,
      qp, kp, vp, Cc, Rr, nullptr, 8, 32);

  scan_phaseA<<<(Bb * NCH * Cc) / 256, 256, 0, stream>>>(kp, vp, decay, hend);
  scan_combine<<<(Bb * Cc) / 256, 256, 0, stream>>>(hend, h0, decayL, Hin, hfinal);
  scan_phaseB<<<(Bb * NCH * Cc) / 256, 256, 0, stream>>>(qp, kp, vp, decay, Hin, ysb);

  // Gout: out = ys @ out_w^T + out_b   (256 blocks; NT=32)
  gemm8p<false, true><<<256, 512, 0, stream>>>(
      ysb, Cc, 0, owT, Cc, 0,
      out, out, out, Cc, Cc, ob, 8, 32);
}

// Round 9
// 261.711 us; speedup vs baseline: 1.0152x; 1.0106x over previous
//
#include <hip/hip_runtime.h>

// RWKV time mixing: LN -> token-shift mix -> 3x low-rank proj -> chunked scan
// -> output GEMM. B=4, T=2048, C=2048, R=256.
// Round 9: GEMM core reverted to r4-exact (ring-4, BK=32, 1 barrier+vmcnt(8)
// per tile, XOR swizzle, setprio) -- measured best (72.2us, MfmaUtil 40%).
// Generalized to multi-problem concat-K: one launch walks npLoop problems'
// K-loops back-to-back in a single warm pipeline (kills G2's fill/drain x3),
// writing C mid-loop at each problem boundary. G1 = grid-level split-K x2.

typedef __attribute__((ext_vector_type(8))) __bf16 bf16x8;
typedef __attribute__((ext_vector_type(4))) float f32x4;

static constexpr int Bb = 4, Tt = 2048, Cc = 2048, Rr = 256;
static constexpr int Mrows = Bb * Tt;      // 8192
static constexpr int NCH = 32, CLEN = 64;  // scan chunking

__device__ __forceinline__ unsigned short f2bf(float f) {
  union { float f; unsigned u; } a; a.f = f;
  unsigned r = (a.u + 0x7FFFu + ((a.u >> 16) & 1u)) >> 16;  // RNE
  return (unsigned short)r;
}
__device__ __forceinline__ float bf2f(unsigned short h) {
  union { unsigned u; float f; } a; a.u = ((unsigned)h) << 16;
  return a.f;
}

__device__ __forceinline__ void gload16(const void* g, void* l) {
  __builtin_amdgcn_global_load_lds(
      (const __attribute__((address_space(1))) void*)g,
      (__attribute__((address_space(3))) void*)l, 16, 0, 0);
}

// ---------------- weight prep ----------------------------------------------
__global__ void prep_weights(const float* __restrict__ wqa, const float* __restrict__ wka,
                             const float* __restrict__ wva, const float* __restrict__ wqb,
                             const float* __restrict__ wkb, const float* __restrict__ wvb,
                             const float* __restrict__ ow,  const float* __restrict__ td,
                             unsigned short* __restrict__ waT, unsigned short* __restrict__ wbT,
                             unsigned short* __restrict__ owT, float* __restrict__ decay,
                             float* __restrict__ decayL) {
  const int g = blockIdx.x * blockDim.x + threadIdx.x;
  const int stride = gridDim.x * blockDim.x;
  for (int i = g; i < 3 * Rr * Cc; i += stride) {
    int c = i & (Cc - 1); int jj = i >> 11; int p = jj >> 8; int r = jj & (Rr - 1);
    const float* w = (p == 0) ? wqa : ((p == 1) ? wka : wva);
    waT[i] = f2bf(w[(size_t)c * Rr + r]);
  }
  for (int i = g; i < 3 * Cc * Rr; i += stride) {
    int r = i & (Rr - 1); int d = (i >> 8) & (Cc - 1); int p = i >> 19;
    const float* w = (p == 0) ? wqb : ((p == 1) ? wkb : wvb);
    wbT[i] = f2bf(w[(size_t)r * Cc + d]);
  }
  for (int i = g; i < Cc * Cc; i += stride) owT[i] = f2bf(ow[i]);
  for (int i = g; i < Cc; i += stride) {
    float e = expf(td[i]);
    decay[i] = expf(-e);
    decayL[i] = expf(-(float)CLEN * e);
  }
}

// ---------------- fused LayerNorm + token-shift mix -------------------------
__global__ __launch_bounds__(256) void lnmix_kernel(
    const float* __restrict__ x, const float* __restrict__ gamma,
    const float* __restrict__ beta, unsigned short* __restrict__ mix) {
  const int m = blockIdx.x;
  const int t = m & (Tt - 1);
  const float* xr = x + (size_t)m * Cc;
  float s0 = 0.f, q0 = 0.f, s1 = 0.f, q1 = 0.f;
  float4 cur[2], prv[2];
#pragma unroll
  for (int r = 0; r < 2; ++r) {
    int i = threadIdx.x + r * 256;
    float4 v = ((const float4*)xr)[i];
    cur[r] = v;
    s0 += v.x + v.y + v.z + v.w;
    q0 += v.x * v.x + v.y * v.y + v.z * v.z + v.w * v.w;
  }
  if (t > 0) {
    const float* xp = xr - Cc;
#pragma unroll
    for (int r = 0; r < 2; ++r) {
      int i = threadIdx.x + r * 256;
      float4 v = ((const float4*)xp)[i];
      prv[r] = v;
      s1 += v.x + v.y + v.z + v.w;
      q1 += v.x * v.x + v.y * v.y + v.z * v.z + v.w * v.w;
    }
  }
#pragma unroll
  for (int off = 32; off; off >>= 1) {
    s0 += __shfl_down(s0, off); q0 += __shfl_down(q0, off);
    s1 += __shfl_down(s1, off); q1 += __shfl_down(q1, off);
  }
  __shared__ float red[4][4];
  __shared__ float bc[4];
  if ((threadIdx.x & 63) == 0) {
    int w = threadIdx.x >> 6;
    red[w][0] = s0; red[w][1] = q0; red[w][2] = s1; red[w][3] = q1;
  }
  __syncthreads();
  if (threadIdx.x == 0) {
    float a0 = 0, b0 = 0, a1 = 0, b1 = 0;
    for (int w = 0; w < 4; ++w) { a0 += red[w][0]; b0 += red[w][1]; a1 += red[w][2]; b1 += red[w][3]; }
    float mu0 = a0 * (1.f / Cc);
    bc[0] = mu0; bc[1] = rsqrtf(b0 * (1.f / Cc) - mu0 * mu0 + 1e-5f);
    float mu1 = a1 * (1.f / Cc);
    bc[2] = mu1; bc[3] = rsqrtf(b1 * (1.f / Cc) - mu1 * mu1 + 1e-5f);
  }
  __syncthreads();
  const float mu0 = bc[0], rs0 = bc[1], mu1 = bc[2], rs1 = bc[3];
#pragma unroll
  for (int r = 0; r < 2; ++r) {
    int i = threadIdx.x + r * 256;
    float4 g = ((const float4*)gamma)[i];
    float4 bb = ((const float4*)beta)[i];
    float4 v = cur[r];
    float mx = (v.x - mu0) * rs0 * g.x + bb.x;
    float my = (v.y - mu0) * rs0 * g.y + bb.y;
    float mz = (v.z - mu0) * rs0 * g.z + bb.z;
    float mw = (v.w - mu0) * rs0 * g.w + bb.w;
    if (t > 0) {
      float4 u = prv[r];
      mx = 0.5f * (mx + (u.x - mu1) * rs1 * g.x + bb.x);
      my = 0.5f * (my + (u.y - mu1) * rs1 * g.y + bb.y);
      mz = 0.5f * (mz + (u.z - mu1) * rs1 * g.z + bb.z);
      mw = 0.5f * (mw + (u.w - mu1) * rs1 * g.w + bb.w);
    } else {
      mx *= 0.5f; my *= 0.5f; mz *= 0.5f; mw *= 0.5f;
    }
    ushort4 o;
    o.x = f2bf(mx); o.y = f2bf(my); o.z = f2bf(mz); o.w = f2bf(mw);
    ((ushort4*)mix)[(size_t)m * 512 + i] = o;
  }
}

// ---------------- 256^2 BK=32 ring-4 multi-problem GEMM ---------------------
// r4-exact core: 512 threads = 8 waves (2M x 4N), wave tile 128x64,
// acc[8][4] f32x4. LDS: 4 ring bufs x (A 256x32 16KB + B 256x32 16KB)=128KB.
// Swizzle: slot s of row r at s ^ ((r>>1)&3); linear gload_lds dest +
// pre-swizzled global source col + swizzled ds_read (0 conflicts, r3/r4).
// One vmcnt(8/4/0) gate + barrier per tile; stage(t+3) -> buf (t+3)&3 whose
// reads (tile t-1) closed by tile t's top barrier.
// Multi-problem: TT = NT2*npLoop tiles; stage cursor wraps saOff/sbOff by
// (strideP - K) at problem boundaries; C written mid-loop per problem.
template <bool STORE_BF16, bool ADD_BIAS>
__global__ __launch_bounds__(512, 1) void gemm_mp(
    const unsigned short* __restrict__ A0, long lda, long aStrideP,
    const unsigned short* __restrict__ B0, long ldb, long bStrideP,
    void* c0, void* c1, void* c2, long ldc, int NT2, int npLoop,
    const float* __restrict__ bias, int nbx, int nby) {
  __shared__ unsigned short lds[4 * 16384];
  const int tid = threadIdx.x;
  const int nwg = gridDim.x;
  const int id = blockIdx.x;
  const int q = nwg >> 3;
  const int swz = (id & 7) * q + (id >> 3);
  const int per = nbx * nby;
  const int pgrid = swz / per;
  const int r2 = swz - pgrid * per;
  const int mblk = r2 / nbx;
  const int nblk = r2 - mblk * nbx;
  const int pgBase = pgrid * npLoop;
  const unsigned short* A  = A0 + (long)pgBase * aStrideP;
  const unsigned short* Bt = B0 + (long)pgBase * bStrideP;
  const long m0 = (long)mblk * 256, n0 = (long)nblk * 256;

  const int lane = tid & 63, wid = tid >> 6;
  const int wm = wid >> 2, wn = wid & 3;
  const int fr = lane & 15, fq = lane >> 4;

  const int srow = tid >> 2;
  const int s_src = (tid & 3) ^ ((tid >> 3) & 3);
  const unsigned short* Ag = A + (m0 + srow) * lda + s_src * 8;
  const unsigned short* Bg = Bt + (n0 + srow) * ldb + s_src * 8;

  const int swzs = fq ^ ((fr >> 1) & 3);
  const unsigned short* aBase = &lds[(wm * 128 + fr) * 32 + swzs * 8];
  const unsigned short* bBase = &lds[8192 + (wn * 64 + fr) * 32 + swzs * 8];

  f32x4 acc[8][4];
#pragma unroll
  for (int i = 0; i < 8; ++i)
#pragma unroll
    for (int j = 0; j < 4; ++j) acc[i][j] = (f32x4){0.f, 0.f, 0.f, 0.f};

  const int TT = NT2 * npLoop;
  const long KEL = (long)NT2 * 32;   // K elements per problem

  auto stage = [&](long aOff, long bOff, int buf) {
    unsigned short* dA = &lds[buf * 16384 + tid * 8];
    unsigned short* dB = &lds[buf * 16384 + 8192 + tid * 8];
    gload16(Ag + aOff, dA);
    gload16(Ag + 128 * lda + aOff, dA + 4096);
    gload16(Bg + bOff, dB);
    gload16(Bg + 128 * ldb + bOff, dB + 4096);
  };

  auto writeC = [&](int pe) {
    void* Cp = (pe == 0) ? c0 : (pe == 1 ? c1 : c2);
#pragma unroll
    for (int j = 0; j < 4; ++j) {
      const long col = n0 + wn * 64 + j * 16 + fr;
      const float bv = ADD_BIAS ? bias[col] : 0.0f;
#pragma unroll
      for (int i = 0; i < 8; ++i) {
        const long row0 = m0 + wm * 128 + i * 16 + fq * 4;
#pragma unroll
        for (int r = 0; r < 4; ++r) {
          float val = acc[i][j][r] + bv;
          if (STORE_BF16)
            ((unsigned short*)Cp)[(row0 + r) * ldc + col] = f2bf(val);
          else
            ((float*)Cp)[(row0 + r) * ldc + col] = val;
        }
      }
    }
  };

  // prologue: stage tiles 0,1,2 (all within problem 0 since NT2 >= 8)
  stage(0, 0, 0);
  stage(32, 32, 1);
  stage(64, 64, 2);
  long saOff = 96, sbOff = 96;
  long skc = 96;
  int rk = 0, rp = 0;

  for (int t = 0; t < TT; ++t) {
    const int rem = TT - 1 - t;
    if (rem >= 2)      asm volatile("s_waitcnt vmcnt(8)" ::: "memory");
    else if (rem == 1) asm volatile("s_waitcnt vmcnt(4)" ::: "memory");
    else               asm volatile("s_waitcnt vmcnt(0)" ::: "memory");
    __builtin_amdgcn_s_barrier();
    __builtin_amdgcn_sched_barrier(0);  // keep ds_reads below the barrier

    // stage first (T3: issue loads before reads+MFMA)
    if (t + 3 < TT) {
      stage(saOff, sbOff, (t + 3) & 3);
      saOff += 32; sbOff += 32; skc += 32;
      if (skc == KEL) { skc = 0; saOff += aStrideP - KEL; sbOff += bStrideP - KEL; }
    }

    const unsigned short* ab = aBase + (t & 3) * 16384;
    const unsigned short* bb = bBase + (t & 3) * 16384;
    bf16x8 bf[4], af[8];
#pragma unroll
    for (int j = 0; j < 4; ++j) bf[j] = *(const bf16x8*)(bb + j * 512);
#pragma unroll
    for (int i = 0; i < 8; ++i) af[i] = *(const bf16x8*)(ab + i * 512);
    __builtin_amdgcn_s_setprio(1);
#pragma unroll
    for (int i = 0; i < 8; ++i)
#pragma unroll
      for (int j = 0; j < 4; ++j)
        acc[i][j] = __builtin_amdgcn_mfma_f32_16x16x32_bf16(af[i], bf[j], acc[i][j], 0, 0, 0);
    __builtin_amdgcn_s_setprio(0);

    // problem boundary: write C, reset acc
    if (++rk == NT2) {
      rk = 0;
      writeC(pgBase + rp);
      ++rp;
      if (rp < npLoop) {
#pragma unroll
        for (int i = 0; i < 8; ++i)
#pragma unroll
          for (int j = 0; j < 4; ++j) acc[i][j] = (f32x4){0.f, 0.f, 0.f, 0.f};
      }
    }
  }
}

// ---------------- split-K combine for G1 ------------------------------------
__global__ void addcvt_kernel(const float* __restrict__ p0, const float* __restrict__ p1,
                              unsigned short* __restrict__ o, int n4) {
  for (int i = blockIdx.x * blockDim.x + threadIdx.x; i < n4; i += gridDim.x * blockDim.x) {
    float4 a = ((const float4*)p0)[i];
    float4 b = ((const float4*)p1)[i];
    ushort4 r;
    r.x = f2bf(a.x + b.x); r.y = f2bf(a.y + b.y);
    r.z = f2bf(a.z + b.z); r.w = f2bf(a.w + b.w);
    ((ushort4*)o)[i] = r;
  }
}

// ---------------- chunked scan ---------------------------------------------
__global__ void scan_phaseA(const unsigned short* __restrict__ k, const unsigned short* __restrict__ v,
                            const float* __restrict__ decay, float* __restrict__ hend) {
  const int g = blockIdx.x * 256 + threadIdx.x;
  const int c = g & (Cc - 1);
  const int j = (g >> 11) & (NCH - 1);
  const int b = g >> 16;
  const float d = decay[c];
  size_t base = ((size_t)(b * Tt + j * CLEN)) * Cc + c;
  float h = 0.f;
#pragma unroll 8
  for (int s = 0; s < CLEN; ++s) {
    size_t idx = base + (size_t)s * Cc;
    float kv = bf2f(k[idx]) * bf2f(v[idx]);
    h = fmaf(d, h, kv);
  }
  hend[(size_t)(b * NCH + j) * Cc + c] = h;
}

__global__ void scan_combine(const float* __restrict__ hend, const float* __restrict__ h0,
                             const float* __restrict__ decayL, float* __restrict__ Hin,
                             float* __restrict__ hfinal) {
  const int g = blockIdx.x * 256 + threadIdx.x;
  const int c = g & (Cc - 1);
  float H = h0[g];
  const float dl = decayL[c];
  const int b = g >> 11;
  for (int j = 0; j < NCH; ++j) {
    size_t idx = (size_t)(b * NCH + j) * Cc + c;
    Hin[idx] = H;
    H = fmaf(dl, H, hend[idx]);
  }
  hfinal[g] = H;
}

__global__ void scan_phaseB(const unsigned short* __restrict__ q, const unsigned short* __restrict__ k,
                            const unsigned short* __restrict__ v, const float* __restrict__ decay,
                            const float* __restrict__ Hin, unsigned short* __restrict__ ys) {
  const int g = blockIdx.x * 256 + threadIdx.x;
  const int c = g & (Cc - 1);
  const int j = (g >> 11) & (NCH - 1);
  const int b = g >> 16;
  const float d = decay[c];
  float h = Hin[(size_t)(b * NCH + j) * Cc + c];
  size_t base = ((size_t)(b * Tt + j * CLEN)) * Cc + c;
#pragma unroll 4
  for (int s = 0; s < CLEN; ++s) {
    size_t idx = base + (size_t)s * Cc;
    float kv = bf2f(k[idx]) * bf2f(v[idx]);
    h = fmaf(d, h, kv);
    float qq = bf2f(q[idx]);
    float sg = 1.f / (1.f + expf(-qq));
    ys[idx] = f2bf(sg * h);
  }
}

// ---------------- launch ----------------------------------------------------
extern "C" void kernel_launch(void* const* d_in, const int* in_sizes, int n_in,
                              void* d_out, int out_size, void* d_ws, size_t ws_size,
                              hipStream_t stream) {
  const float* x   = (const float*)d_in[0];
  const float* h0  = (const float*)d_in[1];
  const float* gam = (const float*)d_in[2];
  const float* bet = (const float*)d_in[3];
  const float* wqa = (const float*)d_in[4];
  const float* wqb = (const float*)d_in[5];
  const float* wka = (const float*)d_in[6];
  const float* wkb = (const float*)d_in[7];
  const float* wva = (const float*)d_in[8];
  const float* wvb = (const float*)d_in[9];
  const float* ow  = (const float*)d_in[10];
  const float* ob  = (const float*)d_in[11];
  const float* td  = (const float*)d_in[12];
  float* out = (float*)d_out;

  char* ws = (char*)d_ws;
  unsigned short* waT   = (unsigned short*)(ws + 0);          //  3,145,728
  unsigned short* wbT   = (unsigned short*)(ws + 3145728);    //  3,145,728
  unsigned short* owT   = (unsigned short*)(ws + 6291456);    //  8,388,608
  float*          decay = (float*)(ws + 14680064);
  float*          decayL= (float*)(ws + 14688256);
  unsigned short* mixb  = (unsigned short*)(ws + 14761984);   // 33,554,432 (reused as ys)
  unsigned short* tmp   = (unsigned short*)(ws + 48316416);   // 12,582,912
  unsigned short* vp    = (unsigned short*)(ws + 60899328);   // 33,554,432
  float*          hend  = (float*)(ws + 94453760);
  float*          Hin   = (float*)(ws + 95502336);
  // staged in d_out (dead before overwritten): G1 f32 partials, then q,k bf16
  float* P0 = (float*)d_out;                                  // 25.2 MB
  float* P1 = P0 + (size_t)Mrows * 768;                       // 25.2 MB
  unsigned short* qp = (unsigned short*)d_out;
  unsigned short* kp = qp + (size_t)Mrows * Cc;
  float* hfinal = out + (size_t)Mrows * Cc;
  unsigned short* ysb = mixb;

  prep_weights<<<1024, 256, 0, stream>>>(wqa, wka, wva, wqb, wkb, wvb, ow, td,
                                         waT, wbT, owT, decay, decayL);
  lnmix_kernel<<<Mrows, 256, 0, stream>>>(x, gam, bet, mixb);

  // G1 split-K x2 (grid-level p): P_p = mix[:, p*1024:(p+1)*1024] @ waT_half
  // 192 blocks = 2p x (nbx=3 x nby=32); NT2=32 (K=1024), npLoop=1
  gemm_mp<false, false><<<192, 512, 0, stream>>>(
      mixb, Cc, 1024, waT, Cc, 1024,
      P0, P1, nullptr, 768, 32, 1, nullptr, 3, 32);
  addcvt_kernel<<<1024, 256, 0, stream>>>(P0, P1, tmp, Mrows * 768 / 4);

  // G2 concat-K: q/k/v = tmp_p @ w_b_p; 256 blocks (nbx=8 x nby=32),
  // NT2=8 (K=256), npLoop=3 -> one warm 24-tile pipeline per block
  gemm_mp<true, false><<<256, 512, 0, stream>>>(
      tmp, 768, 256, wbT, Rr, (long)Cc * Rr,
      qp, kp, vp, Cc, 8, 3, nullptr, 8, 32);

  scan_phaseA<<<(Bb * NCH * Cc) / 256, 256, 0, stream>>>(kp, vp, decay, hend);
  scan_combine<<<(Bb * Cc) / 256, 256, 0, stream>>>(hend, h0, decayL, Hin, hfinal);
  scan_phaseB<<<(Bb * NCH * Cc) / 256, 256, 0, stream>>>(qp, kp, vp, decay, Hin, ysb);

  // Gout: out = ys @ out_w^T + out_b; 256 blocks, NT2=64 (K=2048), npLoop=1
  gemm_mp<false, true><<<256, 512, 0, stream>>>(
      ysb, Cc, 0, owT, Cc, 0,
      out, out, out, Cc, 64, 1, ob, 8, 32);
}

// Round 10
// 255.725 us; speedup vs baseline: 1.0390x; 1.0234x over previous
//
#include <hip/hip_runtime.h>

// RWKV time mixing: LN -> token-shift mix -> 3x low-rank proj -> chunked scan
// -> output GEMM. B=4, T=2048, C=2048, R=256.
// Round 10: r6 base (best total, 244.5us: 256x128 tile, 256 thr, ring-3,
// vmcnt(6), reads-before-stage, XOR swizzle 0-conflict) + minimal
// multi-problem concat-K grafted on (within-problem index sk*32 + rare
// pointer bump at boundaries; mid-loop C write). G2 = one warm 24-tile
// pipeline (512 blocks) instead of 3 cold rounds; G1 = grid split-K x2.

typedef __attribute__((ext_vector_type(8))) __bf16 bf16x8;
typedef __attribute__((ext_vector_type(4))) float f32x4;

static constexpr int Bb = 4, Tt = 2048, Cc = 2048, Rr = 256;
static constexpr int Mrows = Bb * Tt;      // 8192
static constexpr int NCH = 32, CLEN = 64;  // scan chunking

__device__ __forceinline__ unsigned short f2bf(float f) {
  union { float f; unsigned u; } a; a.f = f;
  unsigned r = (a.u + 0x7FFFu + ((a.u >> 16) & 1u)) >> 16;  // RNE
  return (unsigned short)r;
}
__device__ __forceinline__ float bf2f(unsigned short h) {
  union { unsigned u; float f; } a; a.u = ((unsigned)h) << 16;
  return a.f;
}

__device__ __forceinline__ void gload16(const void* g, void* l) {
  __builtin_amdgcn_global_load_lds(
      (const __attribute__((address_space(1))) void*)g,
      (__attribute__((address_space(3))) void*)l, 16, 0, 0);
}

// ---------------- weight prep ----------------------------------------------
__global__ void prep_weights(const float* __restrict__ wqa, const float* __restrict__ wka,
                             const float* __restrict__ wva, const float* __restrict__ wqb,
                             const float* __restrict__ wkb, const float* __restrict__ wvb,
                             const float* __restrict__ ow,  const float* __restrict__ td,
                             unsigned short* __restrict__ waT, unsigned short* __restrict__ wbT,
                             unsigned short* __restrict__ owT, float* __restrict__ decay,
                             float* __restrict__ decayL) {
  const int g = blockIdx.x * blockDim.x + threadIdx.x;
  const int stride = gridDim.x * blockDim.x;
  for (int i = g; i < 3 * Rr * Cc; i += stride) {
    int c = i & (Cc - 1); int jj = i >> 11; int p = jj >> 8; int r = jj & (Rr - 1);
    const float* w = (p == 0) ? wqa : ((p == 1) ? wka : wva);
    waT[i] = f2bf(w[(size_t)c * Rr + r]);
  }
  for (int i = g; i < 3 * Cc * Rr; i += stride) {
    int r = i & (Rr - 1); int d = (i >> 8) & (Cc - 1); int p = i >> 19;
    const float* w = (p == 0) ? wqb : ((p == 1) ? wkb : wvb);
    wbT[i] = f2bf(w[(size_t)r * Cc + d]);
  }
  for (int i = g; i < Cc * Cc; i += stride) owT[i] = f2bf(ow[i]);
  for (int i = g; i < Cc; i += stride) {
    float e = expf(td[i]);
    decay[i] = expf(-e);
    decayL[i] = expf(-(float)CLEN * e);
  }
}

// ---------------- fused LayerNorm + token-shift mix -------------------------
__global__ __launch_bounds__(256) void lnmix_kernel(
    const float* __restrict__ x, const float* __restrict__ gamma,
    const float* __restrict__ beta, unsigned short* __restrict__ mix) {
  const int m = blockIdx.x;
  const int t = m & (Tt - 1);
  const float* xr = x + (size_t)m * Cc;
  float s0 = 0.f, q0 = 0.f, s1 = 0.f, q1 = 0.f;
  float4 cur[2], prv[2];
#pragma unroll
  for (int r = 0; r < 2; ++r) {
    int i = threadIdx.x + r * 256;
    float4 v = ((const float4*)xr)[i];
    cur[r] = v;
    s0 += v.x + v.y + v.z + v.w;
    q0 += v.x * v.x + v.y * v.y + v.z * v.z + v.w * v.w;
  }
  if (t > 0) {
    const float* xp = xr - Cc;
#pragma unroll
    for (int r = 0; r < 2; ++r) {
      int i = threadIdx.x + r * 256;
      float4 v = ((const float4*)xp)[i];
      prv[r] = v;
      s1 += v.x + v.y + v.z + v.w;
      q1 += v.x * v.x + v.y * v.y + v.z * v.z + v.w * v.w;
    }
  }
#pragma unroll
  for (int off = 32; off; off >>= 1) {
    s0 += __shfl_down(s0, off); q0 += __shfl_down(q0, off);
    s1 += __shfl_down(s1, off); q1 += __shfl_down(q1, off);
  }
  __shared__ float red[4][4];
  __shared__ float bc[4];
  if ((threadIdx.x & 63) == 0) {
    int w = threadIdx.x >> 6;
    red[w][0] = s0; red[w][1] = q0; red[w][2] = s1; red[w][3] = q1;
  }
  __syncthreads();
  if (threadIdx.x == 0) {
    float a0 = 0, b0 = 0, a1 = 0, b1 = 0;
    for (int w = 0; w < 4; ++w) { a0 += red[w][0]; b0 += red[w][1]; a1 += red[w][2]; b1 += red[w][3]; }
    float mu0 = a0 * (1.f / Cc);
    bc[0] = mu0; bc[1] = rsqrtf(b0 * (1.f / Cc) - mu0 * mu0 + 1e-5f);
    float mu1 = a1 * (1.f / Cc);
    bc[2] = mu1; bc[3] = rsqrtf(b1 * (1.f / Cc) - mu1 * mu1 + 1e-5f);
  }
  __syncthreads();
  const float mu0 = bc[0], rs0 = bc[1], mu1 = bc[2], rs1 = bc[3];
#pragma unroll
  for (int r = 0; r < 2; ++r) {
    int i = threadIdx.x + r * 256;
    float4 g = ((const float4*)gamma)[i];
    float4 bb = ((const float4*)beta)[i];
    float4 v = cur[r];
    float mx = (v.x - mu0) * rs0 * g.x + bb.x;
    float my = (v.y - mu0) * rs0 * g.y + bb.y;
    float mz = (v.z - mu0) * rs0 * g.z + bb.z;
    float mw = (v.w - mu0) * rs0 * g.w + bb.w;
    if (t > 0) {
      float4 u = prv[r];
      mx = 0.5f * (mx + (u.x - mu1) * rs1 * g.x + bb.x);
      my = 0.5f * (my + (u.y - mu1) * rs1 * g.y + bb.y);
      mz = 0.5f * (mz + (u.z - mu1) * rs1 * g.z + bb.z);
      mw = 0.5f * (mw + (u.w - mu1) * rs1 * g.w + bb.w);
    } else {
      mx *= 0.5f; my *= 0.5f; mz *= 0.5f; mw *= 0.5f;
    }
    ushort4 o;
    o.x = f2bf(mx); o.y = f2bf(my); o.z = f2bf(mz); o.w = f2bf(mw);
    ((ushort4*)mix)[(size_t)m * 512 + i] = o;
  }
}

// ---------------- 256x128 BK=32 ring-3 multi-problem GEMM, 2 blocks/CU ------
// r6-exact core: 256 threads = 4 waves (2M x 2N), wave tile 128x64,
// acc[8][4] f32x4. LDS: 3 ring bufs x (A 256x32 16KB + B 128x32 8KB) = 72KB.
// Swizzle: slot s of row r at s ^ ((r>>1)&3); linear gload_lds dest +
// pre-swizzled global source col + swizzled ds_read (0 conflicts, r3-r6).
// Ring-3: stage(t+2) -> buf (t+2)%3 whose reads (tile t-1) closed by tile t's
// top barrier; vmcnt(6) gates own stage(t); reads issue BEFORE stage (r6).
// Multi-problem: within-problem stage index sk (offset sk*32), pointer bump
// Ag/Bg += strideP at boundaries; C written mid-loop per problem.
template <bool STORE_BF16, bool ADD_BIAS>
__global__ __launch_bounds__(256, 2) void gemm_mp(
    const unsigned short* __restrict__ A0, long lda, long aStrideP,
    const unsigned short* __restrict__ B0, long ldb, long bStrideP,
    void* c0, void* c1, void* c2, long ldc, int NT2, int npLoop,
    const float* __restrict__ bias, int nbx, int nby) {
  __shared__ unsigned short lds[3 * 12288];
  const int tid = threadIdx.x;
  const int nwg = gridDim.x;
  const int id = blockIdx.x;
  const int q = nwg >> 3;
  const int swz = (id & 7) * q + (id >> 3);
  const int per = nbx * nby;
  const int pgrid = swz / per;
  const int r2 = swz - pgrid * per;
  const int mblk = r2 / nbx;
  const int nblk = r2 - mblk * nbx;
  const int pgBase = pgrid * npLoop;
  const long m0 = (long)mblk * 256, n0 = (long)nblk * 128;

  const int lane = tid & 63, wid = tid >> 6;
  const int wm = wid >> 1, wn = wid & 1;
  const int fr = lane & 15, fq = lane >> 4;

  const int srow = tid >> 2;
  const int s_src = (tid & 3) ^ ((tid >> 3) & 3);
  const unsigned short* Ag = A0 + (long)pgBase * aStrideP + (m0 + srow) * lda + s_src * 8;
  const unsigned short* Bg = B0 + (long)pgBase * bStrideP + (n0 + srow) * ldb + s_src * 8;

  const int swzs = fq ^ ((fr >> 1) & 3);
  const unsigned short* aBase = &lds[(wm * 128 + fr) * 32 + swzs * 8];
  const unsigned short* bBase = &lds[8192 + (wn * 64 + fr) * 32 + swzs * 8];

  f32x4 acc[8][4];
#pragma unroll
  for (int i = 0; i < 8; ++i)
#pragma unroll
    for (int j = 0; j < 4; ++j) acc[i][j] = (f32x4){0.f, 0.f, 0.f, 0.f};

  const int TT = NT2 * npLoop;

  auto stage = [&](int kIn, int buf) {
    unsigned short* dA = &lds[buf * 12288 + tid * 8];
    unsigned short* dB = &lds[buf * 12288 + 8192 + tid * 8];
    const long kt = (long)kIn * 32;
#pragma unroll
    for (int l = 0; l < 4; ++l)
      gload16(Ag + (long)(l * 64) * lda + kt, dA + l * 2048);
#pragma unroll
    for (int l = 0; l < 2; ++l)
      gload16(Bg + (long)(l * 64) * ldb + kt, dB + l * 2048);
  };

  auto writeC = [&](int pe) {
    void* Cp = (pe == 0) ? c0 : (pe == 1 ? c1 : c2);
#pragma unroll
    for (int j = 0; j < 4; ++j) {
      const long col = n0 + wn * 64 + j * 16 + fr;
      const float bv = ADD_BIAS ? bias[col] : 0.0f;
#pragma unroll
      for (int i = 0; i < 8; ++i) {
        const long row0 = m0 + wm * 128 + i * 16 + fq * 4;
#pragma unroll
        for (int r = 0; r < 4; ++r) {
          float val = acc[i][j][r] + bv;
          if (STORE_BF16)
            ((unsigned short*)Cp)[(row0 + r) * ldc + col] = f2bf(val);
          else
            ((float*)Cp)[(row0 + r) * ldc + col] = val;
        }
      }
    }
  };

  // prologue: stage tiles 0,1 of problem 0 (12 loads/thread in flight)
  stage(0, 0); stage(1, 1);
  int sk = 2;                 // within-problem index of next tile to stage
  int bufR = 0, bufS = 2;
  int rk = 0, rp = 0;

  for (int t = 0; t < TT; ++t) {
    if (t < TT - 1) asm volatile("s_waitcnt vmcnt(6)" ::: "memory");
    else            asm volatile("s_waitcnt vmcnt(0)" ::: "memory");
    __builtin_amdgcn_s_barrier();
    __builtin_amdgcn_sched_barrier(0);  // keep ds_reads below the barrier

    const unsigned short* ab = aBase + bufR * 12288;
    const unsigned short* bb = bBase + bufR * 12288;

    bf16x8 bf[4], af[8];
#pragma unroll
    for (int j = 0; j < 4; ++j) bf[j] = *(const bf16x8*)(bb + j * 512);
#pragma unroll
    for (int i = 0; i < 8; ++i) af[i] = *(const bf16x8*)(ab + i * 512);
    if (t + 2 < TT) {
      stage(sk, bufS);
      if (++sk == NT2) { sk = 0; Ag += aStrideP; Bg += bStrideP; }
    }
    __builtin_amdgcn_s_setprio(1);
#pragma unroll
    for (int i = 0; i < 8; ++i)
#pragma unroll
      for (int j = 0; j < 4; ++j)
        acc[i][j] = __builtin_amdgcn_mfma_f32_16x16x32_bf16(af[i], bf[j], acc[i][j], 0, 0, 0);
    __builtin_amdgcn_s_setprio(0);

    // problem boundary: write C, reset acc
    if (++rk == NT2) {
      rk = 0;
      writeC(pgBase + rp);
      ++rp;
      if (rp < npLoop) {
#pragma unroll
        for (int i = 0; i < 8; ++i)
#pragma unroll
          for (int j = 0; j < 4; ++j) acc[i][j] = (f32x4){0.f, 0.f, 0.f, 0.f};
      }
    }

    bufR = (bufR == 2) ? 0 : bufR + 1;
    bufS = (bufS == 2) ? 0 : bufS + 1;
  }
}

// ---------------- split-K combine for G1 ------------------------------------
__global__ void addcvt_kernel(const float* __restrict__ p0, const float* __restrict__ p1,
                              unsigned short* __restrict__ o, int n4) {
  for (int i = blockIdx.x * blockDim.x + threadIdx.x; i < n4; i += gridDim.x * blockDim.x) {
    float4 a = ((const float4*)p0)[i];
    float4 b = ((const float4*)p1)[i];
    ushort4 r;
    r.x = f2bf(a.x + b.x); r.y = f2bf(a.y + b.y);
    r.z = f2bf(a.z + b.z); r.w = f2bf(a.w + b.w);
    ((ushort4*)o)[i] = r;
  }
}

// ---------------- chunked scan ---------------------------------------------
__global__ void scan_phaseA(const unsigned short* __restrict__ k, const unsigned short* __restrict__ v,
                            const float* __restrict__ decay, float* __restrict__ hend) {
  const int g = blockIdx.x * 256 + threadIdx.x;
  const int c = g & (Cc - 1);
  const int j = (g >> 11) & (NCH - 1);
  const int b = g >> 16;
  const float d = decay[c];
  size_t base = ((size_t)(b * Tt + j * CLEN)) * Cc + c;
  float h = 0.f;
#pragma unroll 8
  for (int s = 0; s < CLEN; ++s) {
    size_t idx = base + (size_t)s * Cc;
    float kv = bf2f(k[idx]) * bf2f(v[idx]);
    h = fmaf(d, h, kv);
  }
  hend[(size_t)(b * NCH + j) * Cc + c] = h;
}

__global__ void scan_combine(const float* __restrict__ hend, const float* __restrict__ h0,
                             const float* __restrict__ decayL, float* __restrict__ Hin,
                             float* __restrict__ hfinal) {
  const int g = blockIdx.x * 256 + threadIdx.x;
  const int c = g & (Cc - 1);
  float H = h0[g];
  const float dl = decayL[c];
  const int b = g >> 11;
  for (int j = 0; j < NCH; ++j) {
    size_t idx = (size_t)(b * NCH + j) * Cc + c;
    Hin[idx] = H;
    H = fmaf(dl, H, hend[idx]);
  }
  hfinal[g] = H;
}

__global__ void scan_phaseB(const unsigned short* __restrict__ q, const unsigned short* __restrict__ k,
                            const unsigned short* __restrict__ v, const float* __restrict__ decay,
                            const float* __restrict__ Hin, unsigned short* __restrict__ ys) {
  const int g = blockIdx.x * 256 + threadIdx.x;
  const int c = g & (Cc - 1);
  const int j = (g >> 11) & (NCH - 1);
  const int b = g >> 16;
  const float d = decay[c];
  float h = Hin[(size_t)(b * NCH + j) * Cc + c];
  size_t base = ((size_t)(b * Tt + j * CLEN)) * Cc + c;
#pragma unroll 4
  for (int s = 0; s < CLEN; ++s) {
    size_t idx = base + (size_t)s * Cc;
    float kv = bf2f(k[idx]) * bf2f(v[idx]);
    h = fmaf(d, h, kv);
    float qq = bf2f(q[idx]);
    float sg = 1.f / (1.f + expf(-qq));
    ys[idx] = f2bf(sg * h);
  }
}

// ---------------- launch ----------------------------------------------------
extern "C" void kernel_launch(void* const* d_in, const int* in_sizes, int n_in,
                              void* d_out, int out_size, void* d_ws, size_t ws_size,
                              hipStream_t stream) {
  const float* x   = (const float*)d_in[0];
  const float* h0  = (const float*)d_in[1];
  const float* gam = (const float*)d_in[2];
  const float* bet = (const float*)d_in[3];
  const float* wqa = (const float*)d_in[4];
  const float* wqb = (const float*)d_in[5];
  const float* wka = (const float*)d_in[6];
  const float* wkb = (const float*)d_in[7];
  const float* wva = (const float*)d_in[8];
  const float* wvb = (const float*)d_in[9];
  const float* ow  = (const float*)d_in[10];
  const float* ob  = (const float*)d_in[11];
  const float* td  = (const float*)d_in[12];
  float* out = (float*)d_out;

  char* ws = (char*)d_ws;
  unsigned short* waT   = (unsigned short*)(ws + 0);          //  3,145,728
  unsigned short* wbT   = (unsigned short*)(ws + 3145728);    //  3,145,728
  unsigned short* owT   = (unsigned short*)(ws + 6291456);    //  8,388,608
  float*          decay = (float*)(ws + 14680064);
  float*          decayL= (float*)(ws + 14688256);
  unsigned short* mixb  = (unsigned short*)(ws + 14761984);   // 33,554,432 (reused as ys)
  unsigned short* tmp   = (unsigned short*)(ws + 48316416);   // 12,582,912
  unsigned short* vp    = (unsigned short*)(ws + 60899328);   // 33,554,432
  float*          hend  = (float*)(ws + 94453760);
  float*          Hin   = (float*)(ws + 95502336);
  // staged in d_out (dead before overwritten): G1 f32 partials, then q,k bf16
  float* P0 = (float*)d_out;                                  // 25.2 MB
  float* P1 = P0 + (size_t)Mrows * 768;                       // 25.2 MB
  unsigned short* qp = (unsigned short*)d_out;
  unsigned short* kp = qp + (size_t)Mrows * Cc;
  float* hfinal = out + (size_t)Mrows * Cc;
  unsigned short* ysb = mixb;

  prep_weights<<<1024, 256, 0, stream>>>(wqa, wka, wva, wqb, wkb, wvb, ow, td,
                                         waT, wbT, owT, decay, decayL);
  lnmix_kernel<<<Mrows, 256, 0, stream>>>(x, gam, bet, mixb);

  // G1 split-K x2 (grid p): P_p = mix[:, p*1024:(p+1)*1024] @ waT_half
  // 384 blocks = 2p x (nbx=6 x nby=32); NT2=32 (K=1024), npLoop=1
  gemm_mp<false, false><<<384, 256, 0, stream>>>(
      mixb, Cc, 1024, waT, Cc, 1024,
      P0, P1, nullptr, 768, 32, 1, nullptr, 6, 32);
  addcvt_kernel<<<1024, 256, 0, stream>>>(P0, P1, tmp, Mrows * 768 / 4);

  // G2 concat-K: q/k/v = tmp_p @ w_b_p; 512 blocks (nbx=16 x nby=32),
  // NT2=8 (K=256), npLoop=3 -> one warm 24-tile pipeline per block
  gemm_mp<true, false><<<512, 256, 0, stream>>>(
      tmp, 768, 256, wbT, Rr, (long)Cc * Rr,
      qp, kp, vp, Cc, 8, 3, nullptr, 16, 32);

  scan_phaseA<<<(Bb * NCH * Cc) / 256, 256, 0, stream>>>(kp, vp, decay, hend);
  scan_combine<<<(Bb * Cc) / 256, 256, 0, stream>>>(hend, h0, decayL, Hin, hfinal);
  scan_phaseB<<<(Bb * NCH * Cc) / 256, 256, 0, stream>>>(qp, kp, vp, decay, Hin, ysb);

  // Gout: out = ys @ out_w^T + out_b; 512 blocks (nbx=16 x nby=32), NT2=64
  gemm_mp<false, true><<<512, 256, 0, stream>>>(
      ysb, Cc, 0, owT, Cc, 0,
      out, out, out, Cc, 64, 1, ob, 16, 32);
}

// Round 11
// 254.783 us; speedup vs baseline: 1.0428x; 1.0037x over previous
//
#include <hip/hip_runtime.h>

// RWKV time mixing: LN -> token-shift mix -> 3x low-rank proj -> chunked scan
// -> output GEMM. B=4, T=2048, C=2048, R=256.
// Round 11: r6-verbatim gemm_pipe for G1/Gout (measured best). G2 replaced by
// a K-resident kernel: full A panel (256x256 K, 128KB) staged once per block,
// barrier-free nb-loop over 4 output tiles; B register-direct from a
// fragment-packed weight array (wbP, L2-resident, coalesced dwordx4 loads).

typedef __attribute__((ext_vector_type(8))) __bf16 bf16x8;
typedef __attribute__((ext_vector_type(4))) float f32x4;

static constexpr int Bb = 4, Tt = 2048, Cc = 2048, Rr = 256;
static constexpr int Mrows = Bb * Tt;      // 8192
static constexpr int NCH = 32, CLEN = 64;  // scan chunking

__device__ __forceinline__ unsigned short f2bf(float f) {
  union { float f; unsigned u; } a; a.f = f;
  unsigned r = (a.u + 0x7FFFu + ((a.u >> 16) & 1u)) >> 16;  // RNE
  return (unsigned short)r;
}
__device__ __forceinline__ float bf2f(unsigned short h) {
  union { unsigned u; float f; } a; a.u = ((unsigned)h) << 16;
  return a.f;
}

__device__ __forceinline__ void gload16(const void* g, void* l) {
  __builtin_amdgcn_global_load_lds(
      (const __attribute__((address_space(1))) void*)g,
      (__attribute__((address_space(3))) void*)l, 16, 0, 0);
}

// ---------------- weight prep ----------------------------------------------
// waT: [j=3x256][c] = wa_p[c][r]           (BT layout for G1)
// wbP: fragment-packed B for G2: [p][n64(32)][kt(8)][j(4)][lane(64)][e(8)]
//      element = wb_p[kt*32 + (lane>>4)*8 + e][n64*64 + j*16 + (lane&15)]
// owT: [d][c] = ow[d][c]                   (BT layout for Gout)
__global__ void prep_weights(const float* __restrict__ wqa, const float* __restrict__ wka,
                             const float* __restrict__ wva, const float* __restrict__ wqb,
                             const float* __restrict__ wkb, const float* __restrict__ wvb,
                             const float* __restrict__ ow,  const float* __restrict__ td,
                             unsigned short* __restrict__ waT, unsigned short* __restrict__ wbP,
                             unsigned short* __restrict__ owT, float* __restrict__ decay,
                             float* __restrict__ decayL) {
  const int g = blockIdx.x * blockDim.x + threadIdx.x;
  const int stride = gridDim.x * blockDim.x;
  for (int i = g; i < 3 * Rr * Cc; i += stride) {
    int c = i & (Cc - 1); int jj = i >> 11; int p = jj >> 8; int r = jj & (Rr - 1);
    const float* w = (p == 0) ? wqa : ((p == 1) ? wka : wva);
    waT[i] = f2bf(w[(size_t)c * Rr + r]);
  }
  // wbP packing (3 * 2^19 elements)
  for (int i = g; i < 3 * Cc * Rr; i += stride) {
    int e = i & 7;
    int l = (i >> 3) & 63;
    int j = (i >> 9) & 3;
    int kt = (i >> 11) & 7;
    int n64 = (i >> 14) & 31;
    int p = i >> 19;
    const float* w = (p == 0) ? wqb : ((p == 1) ? wkb : wvb);
    int r = kt * 32 + ((l >> 4) << 3) + e;
    int d = n64 * 64 + j * 16 + (l & 15);
    wbP[i] = f2bf(w[(size_t)r * Cc + d]);
  }
  for (int i = g; i < Cc * Cc; i += stride) owT[i] = f2bf(ow[i]);
  for (int i = g; i < Cc; i += stride) {
    float e = expf(td[i]);
    decay[i] = expf(-e);
    decayL[i] = expf(-(float)CLEN * e);
  }
}

// ---------------- fused LayerNorm + token-shift mix -------------------------
__global__ __launch_bounds__(256) void lnmix_kernel(
    const float* __restrict__ x, const float* __restrict__ gamma,
    const float* __restrict__ beta, unsigned short* __restrict__ mix) {
  const int m = blockIdx.x;
  const int t = m & (Tt - 1);
  const float* xr = x + (size_t)m * Cc;
  float s0 = 0.f, q0 = 0.f, s1 = 0.f, q1 = 0.f;
  float4 cur[2], prv[2];
#pragma unroll
  for (int r = 0; r < 2; ++r) {
    int i = threadIdx.x + r * 256;
    float4 v = ((const float4*)xr)[i];
    cur[r] = v;
    s0 += v.x + v.y + v.z + v.w;
    q0 += v.x * v.x + v.y * v.y + v.z * v.z + v.w * v.w;
  }
  if (t > 0) {
    const float* xp = xr - Cc;
#pragma unroll
    for (int r = 0; r < 2; ++r) {
      int i = threadIdx.x + r * 256;
      float4 v = ((const float4*)xp)[i];
      prv[r] = v;
      s1 += v.x + v.y + v.z + v.w;
      q1 += v.x * v.x + v.y * v.y + v.z * v.z + v.w * v.w;
    }
  }
#pragma unroll
  for (int off = 32; off; off >>= 1) {
    s0 += __shfl_down(s0, off); q0 += __shfl_down(q0, off);
    s1 += __shfl_down(s1, off); q1 += __shfl_down(q1, off);
  }
  __shared__ float red[4][4];
  __shared__ float bc[4];
  if ((threadIdx.x & 63) == 0) {
    int w = threadIdx.x >> 6;
    red[w][0] = s0; red[w][1] = q0; red[w][2] = s1; red[w][3] = q1;
  }
  __syncthreads();
  if (threadIdx.x == 0) {
    float a0 = 0, b0 = 0, a1 = 0, b1 = 0;
    for (int w = 0; w < 4; ++w) { a0 += red[w][0]; b0 += red[w][1]; a1 += red[w][2]; b1 += red[w][3]; }
    float mu0 = a0 * (1.f / Cc);
    bc[0] = mu0; bc[1] = rsqrtf(b0 * (1.f / Cc) - mu0 * mu0 + 1e-5f);
    float mu1 = a1 * (1.f / Cc);
    bc[2] = mu1; bc[3] = rsqrtf(b1 * (1.f / Cc) - mu1 * mu1 + 1e-5f);
  }
  __syncthreads();
  const float mu0 = bc[0], rs0 = bc[1], mu1 = bc[2], rs1 = bc[3];
#pragma unroll
  for (int r = 0; r < 2; ++r) {
    int i = threadIdx.x + r * 256;
    float4 g = ((const float4*)gamma)[i];
    float4 bb = ((const float4*)beta)[i];
    float4 v = cur[r];
    float mx = (v.x - mu0) * rs0 * g.x + bb.x;
    float my = (v.y - mu0) * rs0 * g.y + bb.y;
    float mz = (v.z - mu0) * rs0 * g.z + bb.z;
    float mw = (v.w - mu0) * rs0 * g.w + bb.w;
    if (t > 0) {
      float4 u = prv[r];
      mx = 0.5f * (mx + (u.x - mu1) * rs1 * g.x + bb.x);
      my = 0.5f * (my + (u.y - mu1) * rs1 * g.y + bb.y);
      mz = 0.5f * (mz + (u.z - mu1) * rs1 * g.z + bb.z);
      mw = 0.5f * (mw + (u.w - mu1) * rs1 * g.w + bb.w);
    } else {
      mx *= 0.5f; my *= 0.5f; mz *= 0.5f; mw *= 0.5f;
    }
    ushort4 o;
    o.x = f2bf(mx); o.y = f2bf(my); o.z = f2bf(mz); o.w = f2bf(mw);
    ((ushort4*)mix)[(size_t)m * 512 + i] = o;
  }
}

// ---------------- 256x128 BK=32 ring-3 GEMM (r6-verbatim), 2 blocks/CU ------
template <bool STORE_BF16, bool ADD_BIAS>
__global__ __launch_bounds__(256, 2) void gemm_pipe(
    const unsigned short* __restrict__ A0p, long lda, long aStrideP,
    const unsigned short* __restrict__ B0p, long ldb, long bStrideP,
    void* c0, void* c1, void* c2, long ldc, int K,
    const float* __restrict__ bias, int nbx, int nby) {
  __shared__ unsigned short lds[3 * 12288];
  const int tid = threadIdx.x;
  const int nwg = gridDim.x;
  const int id = blockIdx.x;
  const int q = nwg >> 3;
  const int swz = (id & 7) * q + (id >> 3);
  const int per = nbx * nby;
  const int p = swz / per;
  const int r2 = swz - p * per;
  const int mblk = r2 / nbx;
  const int nblk = r2 - mblk * nbx;
  const unsigned short* A  = A0p + (long)p * aStrideP;
  const unsigned short* Bt = B0p + (long)p * bStrideP;
  void* Cout = (p == 0) ? c0 : (p == 1 ? c1 : c2);
  const long m0 = (long)mblk * 256, n0 = (long)nblk * 128;

  const int lane = tid & 63, wid = tid >> 6;
  const int wm = wid >> 1, wn = wid & 1;
  const int fr = lane & 15, fq = lane >> 4;

  const int srow = tid >> 2;
  const int s_src = (tid & 3) ^ ((tid >> 3) & 3);
  const unsigned short* Ag = A + (m0 + srow) * lda + s_src * 8;
  const unsigned short* Bg = Bt + (n0 + srow) * ldb + s_src * 8;

  const int swzs = fq ^ ((fr >> 1) & 3);
  const unsigned short* aBase = &lds[(wm * 128 + fr) * 32 + swzs * 8];
  const unsigned short* bBase = &lds[8192 + (wn * 64 + fr) * 32 + swzs * 8];

  f32x4 acc[8][4];
#pragma unroll
  for (int i = 0; i < 8; ++i)
#pragma unroll
    for (int j = 0; j < 4; ++j) acc[i][j] = (f32x4){0.f, 0.f, 0.f, 0.f};

  const int NT = K >> 5;

  auto stage = [&](int t, int buf) {
    unsigned short* dA = &lds[buf * 12288 + tid * 8];
    unsigned short* dB = &lds[buf * 12288 + 8192 + tid * 8];
    const long kt = (long)t * 32;
#pragma unroll
    for (int l = 0; l < 4; ++l)
      gload16(Ag + (long)(l * 64) * lda + kt, dA + l * 2048);
#pragma unroll
    for (int l = 0; l < 2; ++l)
      gload16(Bg + (long)(l * 64) * ldb + kt, dB + l * 2048);
  };

  stage(0, 0); stage(1, 1);
  int bufR = 0, bufS = 2;

  for (int t = 0; t < NT; ++t) {
    if (t < NT - 1) asm volatile("s_waitcnt vmcnt(6)" ::: "memory");
    else            asm volatile("s_waitcnt vmcnt(0)" ::: "memory");
    __builtin_amdgcn_s_barrier();
    __builtin_amdgcn_sched_barrier(0);

    const unsigned short* ab = aBase + bufR * 12288;
    const unsigned short* bb = bBase + bufR * 12288;

    bf16x8 bf[4], af[8];
#pragma unroll
    for (int j = 0; j < 4; ++j) bf[j] = *(const bf16x8*)(bb + j * 512);
#pragma unroll
    for (int i = 0; i < 8; ++i) af[i] = *(const bf16x8*)(ab + i * 512);
    if (t + 2 < NT) stage(t + 2, bufS);
    __builtin_amdgcn_s_setprio(1);
#pragma unroll
    for (int i = 0; i < 8; ++i)
#pragma unroll
      for (int j = 0; j < 4; ++j)
        acc[i][j] = __builtin_amdgcn_mfma_f32_16x16x32_bf16(af[i], bf[j], acc[i][j], 0, 0, 0);
    __builtin_amdgcn_s_setprio(0);

    bufR = (bufR == 2) ? 0 : bufR + 1;
    bufS = (bufS == 2) ? 0 : bufS + 1;
  }

#pragma unroll
  for (int j = 0; j < 4; ++j) {
    const long col = n0 + wn * 64 + j * 16 + fr;
    const float bv = ADD_BIAS ? bias[col] : 0.0f;
#pragma unroll
    for (int i = 0; i < 8; ++i) {
      const long row0 = m0 + wm * 128 + i * 16 + fq * 4;
#pragma unroll
      for (int r = 0; r < 4; ++r) {
        float val = acc[i][j][r] + bv;
        if (STORE_BF16)
          ((unsigned short*)Cout)[(row0 + r) * ldc + col] = f2bf(val);
        else
          ((float*)Cout)[(row0 + r) * ldc + col] = val;
      }
    }
  }
}

// ---------------- G2: K-resident GEMM (K=256 in LDS, B register-direct) -----
// 512 threads = 8 waves (4M x 2N), wave tile 64x64, acc[4][4] f32x4.
// A panel 256 rows x 256 K = 128KB staged ONCE (XOR-swizzled: 16B slot s of
// row r at s ^ (r&7)); nb-loop over 4 output tiles of 256x128 is barrier-free
// (A-LDS immutable). B frags loaded global->reg from packed wbP (L2-resident,
// coalesced dwordx4 at lane*16). Grid 384 = 32 mblk x 3 p x 4 nbg.
__global__ __launch_bounds__(512, 1) void gemm_g2(
    const unsigned short* __restrict__ tmp, const unsigned short* __restrict__ wbP,
    unsigned short* __restrict__ qo, unsigned short* __restrict__ ko,
    unsigned short* __restrict__ vo) {
  __shared__ unsigned short Al[65536];  // 256 x 256 bf16
  const int tid = threadIdx.x;
  const int nwg = gridDim.x;            // 384
  const int id0 = blockIdx.x;
  const int qq = nwg >> 3;
  const int id = (id0 & 7) * qq + (id0 >> 3);
  const int mblk = id / 12;
  const int rem = id - mblk * 12;
  const int p = rem >> 2;
  const int nbg = rem & 3;

  // ---- A fill: 16 chunks of 16 rows; linear LDS dest, pre-swizzled src col
  {
    const int rowb = tid >> 5;          // 0..15 within chunk
    const int slot = tid & 31;
    const int s_src = slot ^ (rowb & 7);
    const unsigned short* src = tmp + ((size_t)(mblk * 256 + rowb)) * 768 + p * 256 + s_src * 8;
    unsigned short* dst = &Al[(size_t)tid * 8];
#pragma unroll
    for (int c = 0; c < 16; ++c)
      gload16(src + (size_t)c * 16 * 768, dst + c * 4096);
  }
  asm volatile("s_waitcnt vmcnt(0)" ::: "memory");
  __builtin_amdgcn_s_barrier();

  const int lane = tid & 63, wid = tid >> 6;
  const int wm = wid >> 1, wn = wid & 1;
  const int fr = lane & 15, fq = lane >> 4;

  unsigned short* Cout = (p == 0) ? qo : (p == 1 ? ko : vo);

  for (int s = 0; s < 4; ++s) {
    const int nbCol = nbg * 512 + s * 128;
    const int n64 = (nbCol >> 6) + wn;
    const unsigned short* bbase = wbP + ((size_t)(p * 32 + n64) * 8) * 2048 + lane * 8;

    f32x4 acc[4][4];
#pragma unroll
    for (int i = 0; i < 4; ++i)
#pragma unroll
      for (int j = 0; j < 4; ++j) acc[i][j] = (f32x4){0.f, 0.f, 0.f, 0.f};

#pragma unroll
    for (int kt = 0; kt < 8; ++kt) {
      bf16x8 af[4], bf[4];
#pragma unroll
      for (int j = 0; j < 4; ++j)
        bf[j] = *(const bf16x8*)(bbase + kt * 2048 + j * 512);
#pragma unroll
      for (int i = 0; i < 4; ++i) {
        const int row = wm * 64 + i * 16 + fr;
        const int sl = (kt * 4 + fq) ^ (fr & 7);
        af[i] = *(const bf16x8*)&Al[row * 256 + sl * 8];
      }
#pragma unroll
      for (int i = 0; i < 4; ++i)
#pragma unroll
        for (int j = 0; j < 4; ++j)
          acc[i][j] = __builtin_amdgcn_mfma_f32_16x16x32_bf16(af[i], bf[j], acc[i][j], 0, 0, 0);
    }

#pragma unroll
    for (int j = 0; j < 4; ++j) {
      const long col = nbCol + wn * 64 + j * 16 + fr;
#pragma unroll
      for (int i = 0; i < 4; ++i) {
        const long row0 = (long)mblk * 256 + wm * 64 + i * 16 + fq * 4;
#pragma unroll
        for (int r = 0; r < 4; ++r)
          Cout[(row0 + r) * Cc + col] = f2bf(acc[i][j][r]);
      }
    }
  }
}

// ---------------- split-K combine for G1 ------------------------------------
__global__ void addcvt_kernel(const float* __restrict__ p0, const float* __restrict__ p1,
                              unsigned short* __restrict__ o, int n4) {
  for (int i = blockIdx.x * blockDim.x + threadIdx.x; i < n4; i += gridDim.x * blockDim.x) {
    float4 a = ((const float4*)p0)[i];
    float4 b = ((const float4*)p1)[i];
    ushort4 r;
    r.x = f2bf(a.x + b.x); r.y = f2bf(a.y + b.y);
    r.z = f2bf(a.z + b.z); r.w = f2bf(a.w + b.w);
    ((ushort4*)o)[i] = r;
  }
}

// ---------------- chunked scan ---------------------------------------------
__global__ void scan_phaseA(const unsigned short* __restrict__ k, const unsigned short* __restrict__ v,
                            const float* __restrict__ decay, float* __restrict__ hend) {
  const int g = blockIdx.x * 256 + threadIdx.x;
  const int c = g & (Cc - 1);
  const int j = (g >> 11) & (NCH - 1);
  const int b = g >> 16;
  const float d = decay[c];
  size_t base = ((size_t)(b * Tt + j * CLEN)) * Cc + c;
  float h = 0.f;
#pragma unroll 8
  for (int s = 0; s < CLEN; ++s) {
    size_t idx = base + (size_t)s * Cc;
    float kv = bf2f(k[idx]) * bf2f(v[idx]);
    h = fmaf(d, h, kv);
  }
  hend[(size_t)(b * NCH + j) * Cc + c] = h;
}

__global__ void scan_combine(const float* __restrict__ hend, const float* __restrict__ h0,
                             const float* __restrict__ decayL, float* __restrict__ Hin,
                             float* __restrict__ hfinal) {
  const int g = blockIdx.x * 256 + threadIdx.x;
  const int c = g & (Cc - 1);
  float H = h0[g];
  const float dl = decayL[c];
  const int b = g >> 11;
  for (int j = 0; j < NCH; ++j) {
    size_t idx = (size_t)(b * NCH + j) * Cc + c;
    Hin[idx] = H;
    H = fmaf(dl, H, hend[idx]);
  }
  hfinal[g] = H;
}

__global__ void scan_phaseB(const unsigned short* __restrict__ q, const unsigned short* __restrict__ k,
                            const unsigned short* __restrict__ v, const float* __restrict__ decay,
                            const float* __restrict__ Hin, unsigned short* __restrict__ ys) {
  const int g = blockIdx.x * 256 + threadIdx.x;
  const int c = g & (Cc - 1);
  const int j = (g >> 11) & (NCH - 1);
  const int b = g >> 16;
  const float d = decay[c];
  float h = Hin[(size_t)(b * NCH + j) * Cc + c];
  size_t base = ((size_t)(b * Tt + j * CLEN)) * Cc + c;
#pragma unroll 4
  for (int s = 0; s < CLEN; ++s) {
    size_t idx = base + (size_t)s * Cc;
    float kv = bf2f(k[idx]) * bf2f(v[idx]);
    h = fmaf(d, h, kv);
    float qq = bf2f(q[idx]);
    float sg = 1.f / (1.f + expf(-qq));
    ys[idx] = f2bf(sg * h);
  }
}

// ---------------- launch ----------------------------------------------------
extern "C" void kernel_launch(void* const* d_in, const int* in_sizes, int n_in,
                              void* d_out, int out_size, void* d_ws, size_t ws_size,
                              hipStream_t stream) {
  const float* x   = (const float*)d_in[0];
  const float* h0  = (const float*)d_in[1];
  const float* gam = (const float*)d_in[2];
  const float* bet = (const float*)d_in[3];
  const float* wqa = (const float*)d_in[4];
  const float* wqb = (const float*)d_in[5];
  const float* wka = (const float*)d_in[6];
  const float* wkb = (const float*)d_in[7];
  const float* wva = (const float*)d_in[8];
  const float* wvb = (const float*)d_in[9];
  const float* ow  = (const float*)d_in[10];
  const float* ob  = (const float*)d_in[11];
  const float* td  = (const float*)d_in[12];
  float* out = (float*)d_out;

  char* ws = (char*)d_ws;
  unsigned short* waT   = (unsigned short*)(ws + 0);          //  3,145,728
  unsigned short* wbP   = (unsigned short*)(ws + 3145728);    //  3,145,728 (packed)
  unsigned short* owT   = (unsigned short*)(ws + 6291456);    //  8,388,608
  float*          decay = (float*)(ws + 14680064);
  float*          decayL= (float*)(ws + 14688256);
  unsigned short* mixb  = (unsigned short*)(ws + 14761984);   // 33,554,432 (reused as ys)
  unsigned short* tmp   = (unsigned short*)(ws + 48316416);   // 12,582,912
  unsigned short* vp    = (unsigned short*)(ws + 60899328);   // 33,554,432
  float*          hend  = (float*)(ws + 94453760);
  float*          Hin   = (float*)(ws + 95502336);
  // staged in d_out (dead before overwritten): G1 f32 partials, then q,k bf16
  float* P0 = (float*)d_out;                                  // 25.2 MB
  float* P1 = P0 + (size_t)Mrows * 768;                       // 25.2 MB
  unsigned short* qp = (unsigned short*)d_out;
  unsigned short* kp = qp + (size_t)Mrows * Cc;
  float* hfinal = out + (size_t)Mrows * Cc;
  unsigned short* ysb = mixb;

  prep_weights<<<1024, 256, 0, stream>>>(wqa, wka, wva, wqb, wkb, wvb, ow, td,
                                         waT, wbP, owT, decay, decayL);
  lnmix_kernel<<<Mrows, 256, 0, stream>>>(x, gam, bet, mixb);

  // G1 split-K x2 (grid p): P_p = mix[:, p*1024:(p+1)*1024] @ waT_half
  // 384 blocks = 2p x (nbx=6 x nby=32); K=1024
  gemm_pipe<false, false><<<384, 256, 0, stream>>>(
      mixb, Cc, 1024, waT, Cc, 1024,
      P0, P1, nullptr, 768, 1024, nullptr, 6, 32);
  addcvt_kernel<<<1024, 256, 0, stream>>>(P0, P1, tmp, Mrows * 768 / 4);

  // G2: K-resident kernel, 384 blocks (32 mblk x 3 p x 4 nbg)
  gemm_g2<<<384, 512, 0, stream>>>(tmp, wbP, qp, kp, vp);

  scan_phaseA<<<(Bb * NCH * Cc) / 256, 256, 0, stream>>>(kp, vp, decay, hend);
  scan_combine<<<(Bb * Cc) / 256, 256, 0, stream>>>(hend, h0, decayL, Hin, hfinal);
  scan_phaseB<<<(Bb * NCH * Cc) / 256, 256, 0, stream>>>(qp, kp, vp, decay, Hin, ysb);

  // Gout: out = ys @ out_w^T + out_b; 512 blocks (nbx=16 x nby=32), K=2048
  gemm_pipe<false, true><<<512, 256, 0, stream>>>(
      ysb, Cc, 0, owT, Cc, 0,
      out, out, out, Cc, 2048, ob, 16, 32);
}

// Round 12
// 248.769 us; speedup vs baseline: 1.0680x; 1.0242x over previous
//
#include <hip/hip_runtime.h>

// RWKV time mixing: LN -> token-shift mix -> 3x low-rank proj -> chunked scan
// -> output GEMM. B=4, T=2048, C=2048, R=256.
// Round 12: r6-exact everywhere (best measured total). Single change: G1 is
// split-K x4 (768 blocks, K=512 each, bf16 partials in d_out, addcvt4
// combine). Rationale: G1 at 384 blocks/K=1024 ran 3800 cyc/tile vs Gout's
// 1415 (L2 working set ~7MB > 4MB per-XCD + 1.5/CU occupancy); K=512 panels
// bring the per-XCD resident set to ~3.4MB and the grid to 1.5 clean rounds.

typedef __attribute__((ext_vector_type(8))) __bf16 bf16x8;
typedef __attribute__((ext_vector_type(4))) float f32x4;

static constexpr int Bb = 4, Tt = 2048, Cc = 2048, Rr = 256;
static constexpr int Mrows = Bb * Tt;      // 8192
static constexpr int NCH = 32, CLEN = 64;  // scan chunking

__device__ __forceinline__ unsigned short f2bf(float f) {
  union { float f; unsigned u; } a; a.f = f;
  unsigned r = (a.u + 0x7FFFu + ((a.u >> 16) & 1u)) >> 16;  // RNE
  return (unsigned short)r;
}
__device__ __forceinline__ float bf2f(unsigned short h) {
  union { unsigned u; float f; } a; a.u = ((unsigned)h) << 16;
  return a.f;
}

__device__ __forceinline__ void gload16(const void* g, void* l) {
  __builtin_amdgcn_global_load_lds(
      (const __attribute__((address_space(1))) void*)g,
      (__attribute__((address_space(3))) void*)l, 16, 0, 0);
}

// ---------------- weight prep (r6 version) ----------------------------------
__global__ void prep_weights(const float* __restrict__ wqa, const float* __restrict__ wka,
                             const float* __restrict__ wva, const float* __restrict__ wqb,
                             const float* __restrict__ wkb, const float* __restrict__ wvb,
                             const float* __restrict__ ow,  const float* __restrict__ td,
                             unsigned short* __restrict__ waT, unsigned short* __restrict__ wbT,
                             unsigned short* __restrict__ owT, float* __restrict__ decay,
                             float* __restrict__ decayL) {
  const int g = blockIdx.x * blockDim.x + threadIdx.x;
  const int stride = gridDim.x * blockDim.x;
  for (int i = g; i < 3 * Rr * Cc; i += stride) {
    int c = i & (Cc - 1); int jj = i >> 11; int p = jj >> 8; int r = jj & (Rr - 1);
    const float* w = (p == 0) ? wqa : ((p == 1) ? wka : wva);
    waT[i] = f2bf(w[(size_t)c * Rr + r]);
  }
  for (int i = g; i < 3 * Cc * Rr; i += stride) {
    int r = i & (Rr - 1); int d = (i >> 8) & (Cc - 1); int p = i >> 19;
    const float* w = (p == 0) ? wqb : ((p == 1) ? wkb : wvb);
    wbT[i] = f2bf(w[(size_t)r * Cc + d]);
  }
  for (int i = g; i < Cc * Cc; i += stride) owT[i] = f2bf(ow[i]);
  for (int i = g; i < Cc; i += stride) {
    float e = expf(td[i]);
    decay[i] = expf(-e);
    decayL[i] = expf(-(float)CLEN * e);
  }
}

// ---------------- fused LayerNorm + token-shift mix (r6 version) ------------
__global__ __launch_bounds__(256) void lnmix_kernel(
    const float* __restrict__ x, const float* __restrict__ gamma,
    const float* __restrict__ beta, unsigned short* __restrict__ mix) {
  const int m = blockIdx.x;
  const int t = m & (Tt - 1);
  const float* xr = x + (size_t)m * Cc;
  float s0 = 0.f, q0 = 0.f, s1 = 0.f, q1 = 0.f;
  float4 cur[2], prv[2];
#pragma unroll
  for (int r = 0; r < 2; ++r) {
    int i = threadIdx.x + r * 256;
    float4 v = ((const float4*)xr)[i];
    cur[r] = v;
    s0 += v.x + v.y + v.z + v.w;
    q0 += v.x * v.x + v.y * v.y + v.z * v.z + v.w * v.w;
  }
  if (t > 0) {
    const float* xp = xr - Cc;
#pragma unroll
    for (int r = 0; r < 2; ++r) {
      int i = threadIdx.x + r * 256;
      float4 v = ((const float4*)xp)[i];
      prv[r] = v;
      s1 += v.x + v.y + v.z + v.w;
      q1 += v.x * v.x + v.y * v.y + v.z * v.z + v.w * v.w;
    }
  }
#pragma unroll
  for (int off = 32; off; off >>= 1) {
    s0 += __shfl_down(s0, off); q0 += __shfl_down(q0, off);
    s1 += __shfl_down(s1, off); q1 += __shfl_down(q1, off);
  }
  __shared__ float red[4][4];
  __shared__ float bc[4];
  if ((threadIdx.x & 63) == 0) {
    int w = threadIdx.x >> 6;
    red[w][0] = s0; red[w][1] = q0; red[w][2] = s1; red[w][3] = q1;
  }
  __syncthreads();
  if (threadIdx.x == 0) {
    float a0 = 0, b0 = 0, a1 = 0, b1 = 0;
    for (int w = 0; w < 4; ++w) { a0 += red[w][0]; b0 += red[w][1]; a1 += red[w][2]; b1 += red[w][3]; }
    float mu0 = a0 * (1.f / Cc);
    bc[0] = mu0; bc[1] = rsqrtf(b0 * (1.f / Cc) - mu0 * mu0 + 1e-5f);
    float mu1 = a1 * (1.f / Cc);
    bc[2] = mu1; bc[3] = rsqrtf(b1 * (1.f / Cc) - mu1 * mu1 + 1e-5f);
  }
  __syncthreads();
  const float mu0 = bc[0], rs0 = bc[1], mu1 = bc[2], rs1 = bc[3];
#pragma unroll
  for (int r = 0; r < 2; ++r) {
    int i = threadIdx.x + r * 256;
    float4 g = ((const float4*)gamma)[i];
    float4 bb = ((const float4*)beta)[i];
    float4 v = cur[r];
    float mx = (v.x - mu0) * rs0 * g.x + bb.x;
    float my = (v.y - mu0) * rs0 * g.y + bb.y;
    float mz = (v.z - mu0) * rs0 * g.z + bb.z;
    float mw = (v.w - mu0) * rs0 * g.w + bb.w;
    if (t > 0) {
      float4 u = prv[r];
      mx = 0.5f * (mx + (u.x - mu1) * rs1 * g.x + bb.x);
      my = 0.5f * (my + (u.y - mu1) * rs1 * g.y + bb.y);
      mz = 0.5f * (mz + (u.z - mu1) * rs1 * g.z + bb.z);
      mw = 0.5f * (mw + (u.w - mu1) * rs1 * g.w + bb.w);
    } else {
      mx *= 0.5f; my *= 0.5f; mz *= 0.5f; mw *= 0.5f;
    }
    ushort4 o;
    o.x = f2bf(mx); o.y = f2bf(my); o.z = f2bf(mz); o.w = f2bf(mw);
    ((ushort4*)mix)[(size_t)m * 512 + i] = o;
  }
}

// ---------------- 256x128 BK=32 ring-3 GEMM (r6 core + 4th output) ----------
// 256 threads = 4 waves (2M x 2N), wave tile 128x64, acc[8][4] f32x4.
// LDS: 3 ring bufs x (A 256x32 16KB + B 128x32 8KB) = 72KB -> 2 blk/CU.
// Swizzle: slot s of row r at s ^ ((r>>1)&3); linear gload_lds dest +
// pre-swizzled global source col + swizzled ds_read (0 conflicts, r3-r11).
// Ring-3: stage(t+2) -> buf whose reads (tile t-1) closed by tile t's top
// barrier; vmcnt(6) gates own stage(t); reads issue BEFORE stage.
template <bool STORE_BF16, bool ADD_BIAS>
__global__ __launch_bounds__(256, 2) void gemm_pipe(
    const unsigned short* __restrict__ A0p, long lda, long aStrideP,
    const unsigned short* __restrict__ B0p, long ldb, long bStrideP,
    void* c0, void* c1, void* c2, void* c3, long ldc, int K,
    const float* __restrict__ bias, int nbx, int nby) {
  __shared__ unsigned short lds[3 * 12288];
  const int tid = threadIdx.x;
  const int nwg = gridDim.x;
  const int id = blockIdx.x;
  const int q = nwg >> 3;
  const int swz = (id & 7) * q + (id >> 3);
  const int per = nbx * nby;
  const int p = swz / per;
  const int r2 = swz - p * per;
  const int mblk = r2 / nbx;
  const int nblk = r2 - mblk * nbx;
  const unsigned short* A  = A0p + (long)p * aStrideP;
  const unsigned short* Bt = B0p + (long)p * bStrideP;
  void* Cout = (p == 0) ? c0 : (p == 1 ? c1 : (p == 2 ? c2 : c3));
  const long m0 = (long)mblk * 256, n0 = (long)nblk * 128;

  const int lane = tid & 63, wid = tid >> 6;
  const int wm = wid >> 1, wn = wid & 1;
  const int fr = lane & 15, fq = lane >> 4;

  const int srow = tid >> 2;
  const int s_src = (tid & 3) ^ ((tid >> 3) & 3);
  const unsigned short* Ag = A + (m0 + srow) * lda + s_src * 8;
  const unsigned short* Bg = Bt + (n0 + srow) * ldb + s_src * 8;

  const int swzs = fq ^ ((fr >> 1) & 3);
  const unsigned short* aBase = &lds[(wm * 128 + fr) * 32 + swzs * 8];
  const unsigned short* bBase = &lds[8192 + (wn * 64 + fr) * 32 + swzs * 8];

  f32x4 acc[8][4];
#pragma unroll
  for (int i = 0; i < 8; ++i)
#pragma unroll
    for (int j = 0; j < 4; ++j) acc[i][j] = (f32x4){0.f, 0.f, 0.f, 0.f};

  const int NT = K >> 5;

  auto stage = [&](int t, int buf) {
    unsigned short* dA = &lds[buf * 12288 + tid * 8];
    unsigned short* dB = &lds[buf * 12288 + 8192 + tid * 8];
    const long kt = (long)t * 32;
#pragma unroll
    for (int l = 0; l < 4; ++l)
      gload16(Ag + (long)(l * 64) * lda + kt, dA + l * 2048);
#pragma unroll
    for (int l = 0; l < 2; ++l)
      gload16(Bg + (long)(l * 64) * ldb + kt, dB + l * 2048);
  };

  stage(0, 0); stage(1, 1);
  int bufR = 0, bufS = 2;

  for (int t = 0; t < NT; ++t) {
    if (t < NT - 1) asm volatile("s_waitcnt vmcnt(6)" ::: "memory");
    else            asm volatile("s_waitcnt vmcnt(0)" ::: "memory");
    __builtin_amdgcn_s_barrier();
    __builtin_amdgcn_sched_barrier(0);

    const unsigned short* ab = aBase + bufR * 12288;
    const unsigned short* bb = bBase + bufR * 12288;

    bf16x8 bf[4], af[8];
#pragma unroll
    for (int j = 0; j < 4; ++j) bf[j] = *(const bf16x8*)(bb + j * 512);
#pragma unroll
    for (int i = 0; i < 8; ++i) af[i] = *(const bf16x8*)(ab + i * 512);
    if (t + 2 < NT) stage(t + 2, bufS);
    __builtin_amdgcn_s_setprio(1);
#pragma unroll
    for (int i = 0; i < 8; ++i)
#pragma unroll
      for (int j = 0; j < 4; ++j)
        acc[i][j] = __builtin_amdgcn_mfma_f32_16x16x32_bf16(af[i], bf[j], acc[i][j], 0, 0, 0);
    __builtin_amdgcn_s_setprio(0);

    bufR = (bufR == 2) ? 0 : bufR + 1;
    bufS = (bufS == 2) ? 0 : bufS + 1;
  }

#pragma unroll
  for (int j = 0; j < 4; ++j) {
    const long col = n0 + wn * 64 + j * 16 + fr;
    const float bv = ADD_BIAS ? bias[col] : 0.0f;
#pragma unroll
    for (int i = 0; i < 8; ++i) {
      const long row0 = m0 + wm * 128 + i * 16 + fq * 4;
#pragma unroll
      for (int r = 0; r < 4; ++r) {
        float val = acc[i][j][r] + bv;
        if (STORE_BF16)
          ((unsigned short*)Cout)[(row0 + r) * ldc + col] = f2bf(val);
        else
          ((float*)Cout)[(row0 + r) * ldc + col] = val;
      }
    }
  }
}

// ---------------- split-K x4 combine for G1 ---------------------------------
__global__ void addcvt4_kernel(const unsigned short* __restrict__ t0,
                               const unsigned short* __restrict__ t1,
                               const unsigned short* __restrict__ t2,
                               const unsigned short* __restrict__ t3,
                               unsigned short* __restrict__ o, int n8) {
  for (int i = blockIdx.x * blockDim.x + threadIdx.x; i < n8; i += gridDim.x * blockDim.x) {
    ushort4 a0 = ((const ushort4*)t0)[2 * i],     b0 = ((const ushort4*)t0)[2 * i + 1];
    ushort4 a1 = ((const ushort4*)t1)[2 * i],     b1 = ((const ushort4*)t1)[2 * i + 1];
    ushort4 a2 = ((const ushort4*)t2)[2 * i],     b2 = ((const ushort4*)t2)[2 * i + 1];
    ushort4 a3 = ((const ushort4*)t3)[2 * i],     b3 = ((const ushort4*)t3)[2 * i + 1];
    ushort4 ra, rb;
    ra.x = f2bf(bf2f(a0.x) + bf2f(a1.x) + bf2f(a2.x) + bf2f(a3.x));
    ra.y = f2bf(bf2f(a0.y) + bf2f(a1.y) + bf2f(a2.y) + bf2f(a3.y));
    ra.z = f2bf(bf2f(a0.z) + bf2f(a1.z) + bf2f(a2.z) + bf2f(a3.z));
    ra.w = f2bf(bf2f(a0.w) + bf2f(a1.w) + bf2f(a2.w) + bf2f(a3.w));
    rb.x = f2bf(bf2f(b0.x) + bf2f(b1.x) + bf2f(b2.x) + bf2f(b3.x));
    rb.y = f2bf(bf2f(b0.y) + bf2f(b1.y) + bf2f(b2.y) + bf2f(b3.y));
    rb.z = f2bf(bf2f(b0.z) + bf2f(b1.z) + bf2f(b2.z) + bf2f(b3.z));
    rb.w = f2bf(bf2f(b0.w) + bf2f(b1.w) + bf2f(b2.w) + bf2f(b3.w));
    ((ushort4*)o)[2 * i] = ra;
    ((ushort4*)o)[2 * i + 1] = rb;
  }
}

// ---------------- chunked scan ---------------------------------------------
__global__ void scan_phaseA(const unsigned short* __restrict__ k, const unsigned short* __restrict__ v,
                            const float* __restrict__ decay, float* __restrict__ hend) {
  const int g = blockIdx.x * 256 + threadIdx.x;
  const int c = g & (Cc - 1);
  const int j = (g >> 11) & (NCH - 1);
  const int b = g >> 16;
  const float d = decay[c];
  size_t base = ((size_t)(b * Tt + j * CLEN)) * Cc + c;
  float h = 0.f;
#pragma unroll 8
  for (int s = 0; s < CLEN; ++s) {
    size_t idx = base + (size_t)s * Cc;
    float kv = bf2f(k[idx]) * bf2f(v[idx]);
    h = fmaf(d, h, kv);
  }
  hend[(size_t)(b * NCH + j) * Cc + c] = h;
}

__global__ void scan_combine(const float* __restrict__ hend, const float* __restrict__ h0,
                             const float* __restrict__ decayL, float* __restrict__ Hin,
                             float* __restrict__ hfinal) {
  const int g = blockIdx.x * 256 + threadIdx.x;
  const int c = g & (Cc - 1);
  float H = h0[g];
  const float dl = decayL[c];
  const int b = g >> 11;
  for (int j = 0; j < NCH; ++j) {
    size_t idx = (size_t)(b * NCH + j) * Cc + c;
    Hin[idx] = H;
    H = fmaf(dl, H, hend[idx]);
  }
  hfinal[g] = H;
}

__global__ void scan_phaseB(const unsigned short* __restrict__ q, const unsigned short* __restrict__ k,
                            const unsigned short* __restrict__ v, const float* __restrict__ decay,
                            const float* __restrict__ Hin, unsigned short* __restrict__ ys) {
  const int g = blockIdx.x * 256 + threadIdx.x;
  const int c = g & (Cc - 1);
  const int j = (g >> 11) & (NCH - 1);
  const int b = g >> 16;
  const float d = decay[c];
  float h = Hin[(size_t)(b * NCH + j) * Cc + c];
  size_t base = ((size_t)(b * Tt + j * CLEN)) * Cc + c;
#pragma unroll 4
  for (int s = 0; s < CLEN; ++s) {
    size_t idx = base + (size_t)s * Cc;
    float kv = bf2f(k[idx]) * bf2f(v[idx]);
    h = fmaf(d, h, kv);
    float qq = bf2f(q[idx]);
    float sg = 1.f / (1.f + expf(-qq));
    ys[idx] = f2bf(sg * h);
  }
}

// ---------------- launch ----------------------------------------------------
extern "C" void kernel_launch(void* const* d_in, const int* in_sizes, int n_in,
                              void* d_out, int out_size, void* d_ws, size_t ws_size,
                              hipStream_t stream) {
  const float* x   = (const float*)d_in[0];
  const float* h0  = (const float*)d_in[1];
  const float* gam = (const float*)d_in[2];
  const float* bet = (const float*)d_in[3];
  const float* wqa = (const float*)d_in[4];
  const float* wqb = (const float*)d_in[5];
  const float* wka = (const float*)d_in[6];
  const float* wkb = (const float*)d_in[7];
  const float* wva = (const float*)d_in[8];
  const float* wvb = (const float*)d_in[9];
  const float* ow  = (const float*)d_in[10];
  const float* ob  = (const float*)d_in[11];
  const float* td  = (const float*)d_in[12];
  float* out = (float*)d_out;

  char* ws = (char*)d_ws;
  unsigned short* waT   = (unsigned short*)(ws + 0);          //  3,145,728
  unsigned short* wbT   = (unsigned short*)(ws + 3145728);    //  3,145,728
  unsigned short* owT   = (unsigned short*)(ws + 6291456);    //  8,388,608
  float*          decay = (float*)(ws + 14680064);
  float*          decayL= (float*)(ws + 14688256);
  unsigned short* mixb  = (unsigned short*)(ws + 14761984);   // 33,554,432 (reused as ys)
  unsigned short* tmp   = (unsigned short*)(ws + 48316416);   // 12,582,912
  unsigned short* vp    = (unsigned short*)(ws + 60899328);   // 33,554,432
  float*          hend  = (float*)(ws + 94453760);
  float*          Hin   = (float*)(ws + 95502336);
  // staged in d_out (dead before overwritten): G1 bf16 partials T0..T3
  // (4 x 12.58 MB = 50.3 MB), then q,k bf16 (addcvt4 reads partials first)
  unsigned short* T0 = (unsigned short*)d_out;
  unsigned short* T1 = T0 + (size_t)Mrows * 768;
  unsigned short* T2 = T1 + (size_t)Mrows * 768;
  unsigned short* T3 = T2 + (size_t)Mrows * 768;
  unsigned short* qp = (unsigned short*)d_out;
  unsigned short* kp = qp + (size_t)Mrows * Cc;
  float* hfinal = out + (size_t)Mrows * Cc;
  unsigned short* ysb = mixb;

  prep_weights<<<1024, 256, 0, stream>>>(wqa, wka, wva, wqb, wkb, wvb, ow, td,
                                         waT, wbT, owT, decay, decayL);
  lnmix_kernel<<<Mrows, 256, 0, stream>>>(x, gam, bet, mixb);

  // G1 split-K x4 (grid p): T_p = mix[:, p*512:(p+1)*512] @ waT[:, p*512:...]
  // 768 blocks = 4p x (nbx=6 x nby=32); K=512 each (NT=16), bf16 partials
  gemm_pipe<true, false><<<768, 256, 0, stream>>>(
      mixb, Cc, 512, waT, Cc, 512,
      T0, T1, T2, T3, 768, 512, nullptr, 6, 32);
  addcvt4_kernel<<<1024, 256, 0, stream>>>(T0, T1, T2, T3, tmp, Mrows * 768 / 8);

  // G2 (r6 config): q/k/v = tmp_p @ w_b_p; 1536 blocks, K=256
  gemm_pipe<true, false><<<1536, 256, 0, stream>>>(
      tmp, 768, 256, wbT, Rr, (long)Cc * Rr,
      qp, kp, vp, nullptr, Cc, 256, nullptr, 16, 32);

  scan_phaseA<<<(Bb * NCH * Cc) / 256, 256, 0, stream>>>(kp, vp, decay, hend);
  scan_combine<<<(Bb * Cc) / 256, 256, 0, stream>>>(hend, h0, decayL, Hin, hfinal);
  scan_phaseB<<<(Bb * NCH * Cc) / 256, 256, 0, stream>>>(qp, kp, vp, decay, Hin, ysb);

  // Gout (r6 config): out = ys @ out_w^T + out_b; 512 blocks, K=2048
  gemm_pipe<false, true><<<512, 256, 0, stream>>>(
      ysb, Cc, 0, owT, Cc, 0,
      out, out, out, nullptr, Cc, 2048, ob, 16, 32);
}